// Round 1
// baseline (970.692 us; speedup 1.0000x reference)
//
#include <hip/hip_runtime.h>
#include <math.h>

#define N_NODES 100000
#define N_EDGES 1600000
#define IN_C    128
#define HID     256
#define KEIG    64
#define OUT_C   16

#define TRANS_BLOCKS   ((N_NODES + 63) / 64)
#define SCATTER_BLOCKS 4096
#define SM_BLOCKS      1024
#define CUT_BLOCKS     2048
#define SS_BLOCKS      256
#define OUT_BLOCKS     ((N_NODES + 255) / 256)

__device__ __forceinline__ float wave_sum(float v) {
#pragma unroll
    for (int m = 32; m; m >>= 1) v += __shfl_xor(v, m, 64);
    return v;
}
__device__ __forceinline__ float wave_max(float v) {
#pragma unroll
    for (int m = 32; m; m >>= 1) v = fmaxf(v, __shfl_xor(v, m, 64));
    return v;
}

// Weff[k][o]: k<128 -> sum_c mlpx_W[c,k]*finW[o,c];  k in [128,192) -> finW[o, 256+(k-128)]
// beff[o] = finb[o] + sum_c mlpx_b[c]*finW[o,c]
__global__ void prep_weff(const float* __restrict__ mlpxW, const float* __restrict__ mlpxb,
                          const float* __restrict__ finW, const float* __restrict__ finb,
                          float* __restrict__ Weff, float* __restrict__ beff) {
    int t = blockIdx.x * blockDim.x + threadIdx.x;
    const int NW = (IN_C + KEIG) * OUT_C;
    if (t < NW) {
        int k = t >> 4, o = t & 15;
        float acc;
        if (k < IN_C) {
            acc = 0.f;
            for (int c = 0; c < HID; ++c)
                acc += mlpxW[c * IN_C + k] * finW[o * (HID + KEIG) + c];
        } else {
            acc = finW[o * (HID + KEIG) + HID + (k - IN_C)];
        }
        Weff[k * OUT_C + o] = acc;
    }
    int tb = t - NW;
    if (tb >= 0 && tb < OUT_C) {
        float acc = finb[tb];
        for (int c = 0; c < HID; ++c) acc += mlpxb[c] * finW[tb * (HID + KEIG) + c];
        beff[tb] = acc;
    }
}

// MLP_W [64, N] -> WT [N, 64]
__global__ void transpose_w(const float* __restrict__ W, float* __restrict__ WT) {
    __shared__ float tile[64][65];
    int n0 = blockIdx.x * 64;
    int t = threadIdx.x;
    int tn = t & 63, tq = t >> 6;
#pragma unroll
    for (int kk = 0; kk < 16; ++kk) {
        int k = tq * 16 + kk;
        int n = n0 + tn;
        tile[k][tn] = (n < N_NODES) ? W[(long long)k * N_NODES + n] : 0.f;
    }
    __syncthreads();
    int tk = t & 63;
#pragma unroll
    for (int ii = 0; ii < 16; ++ii) {
        int n = n0 + tq * 16 + ii;
        if (n < N_NODES) WT[(long long)n * 64 + tk] = tile[tk][tq * 16 + ii];
    }
}

// xA init to bias; zero deg and SS (ws is poisoned 0xAA before every call)
__global__ void init_ws(float* __restrict__ xA, float* __restrict__ deg,
                        float* __restrict__ SS, const float* __restrict__ MLPb) {
    long long stride = (long long)gridDim.x * blockDim.x;
    for (long long i = (long long)blockIdx.x * blockDim.x + threadIdx.x;
         i < (long long)N_NODES * 64; i += stride) {
        xA[i] = MLPb[i & 63];
        if (i < N_NODES) deg[i] = 0.f;
        if (i < 4096) SS[i] = 0.f;
    }
}

// one wave per edge: xA[col] += WT[row]; deg[col] += 1
__global__ void scatter_edges(const int* __restrict__ ei, const float* __restrict__ WT,
                              float* __restrict__ xA, float* __restrict__ deg) {
    int lane = threadIdx.x & 63;
    int gw = (blockIdx.x * blockDim.x + threadIdx.x) >> 6;
    int nw = (gridDim.x * blockDim.x) >> 6;
    for (int e = gw; e < N_EDGES; e += nw) {
        int r = ei[e];
        int c = ei[N_EDGES + e];
        float v = WT[(long long)r * 64 + lane];
        atomicAdd(&xA[(long long)c * 64 + lane], v);
        if (lane == 0) atomicAdd(&deg[c], 1.f);
    }
}

// wave per row: S = softmax(xA); accumulate deg_term partials per block
__global__ void softmax_rows(const float* __restrict__ xA, const float* __restrict__ deg,
                             float* __restrict__ S, float* __restrict__ dtp) {
    int lane = threadIdx.x & 63;
    int wib = threadIdx.x >> 6;
    int gw = (blockIdx.x * blockDim.x + threadIdx.x) >> 6;
    int nw = (gridDim.x * blockDim.x) >> 6;
    float dacc = 0.f;
    for (int r = gw; r < N_NODES; r += nw) {
        float v = xA[(long long)r * 64 + lane];
        float m = wave_max(v);
        float e = __expf(v - m);
        float s = wave_sum(e);
        float sv = e / s;
        S[(long long)r * 64 + lane] = sv;
        dacc += deg[r] * sv * sv;
    }
    dacc = wave_sum(dacc);
    __shared__ float red[4];
    if (lane == 0) red[wib] = dacc;
    __syncthreads();
    if (threadIdx.x == 0) dtp[blockIdx.x] = red[0] + red[1] + red[2] + red[3];
}

// cut = sum_e dot(S[col], S[row]); per-lane accumulate, block partial
__global__ void cut_edges(const int* __restrict__ ei, const float* __restrict__ S,
                          float* __restrict__ cutp) {
    int lane = threadIdx.x & 63;
    int wib = threadIdx.x >> 6;
    int gw = (blockIdx.x * blockDim.x + threadIdx.x) >> 6;
    int nw = (gridDim.x * blockDim.x) >> 6;
    float acc = 0.f;
    for (int e = gw; e < N_EDGES; e += nw) {
        int r = ei[e];
        int c = ei[N_EDGES + e];
        acc += S[(long long)c * 64 + lane] * S[(long long)r * 64 + lane];
    }
    acc = wave_sum(acc);
    __shared__ float red[4];
    if (lane == 0) red[wib] = acc;
    __syncthreads();
    if (threadIdx.x == 0) cutp[blockIdx.x] = red[0] + red[1] + red[2] + red[3];
}

// SS = S^T S  (64x64), atomic accumulate of per-block partial products
__global__ void ss_kernel(const float* __restrict__ S, float* __restrict__ SS) {
    __shared__ float Sr[32][65];
    int t = threadIdx.x;
    int a = t & 63, bq = t >> 6;
    float acc[16];
#pragma unroll
    for (int j = 0; j < 16; ++j) acc[j] = 0.f;
    for (int base = blockIdx.x * 32; base < N_NODES; base += gridDim.x * 32) {
        int nr = min(32, N_NODES - base);
        for (int i = t; i < 32 * 64; i += 256) {
            int rr = i >> 6, cc = i & 63;
            Sr[rr][cc] = (rr < nr) ? S[(long long)(base + rr) * 64 + cc] : 0.f;
        }
        __syncthreads();
        for (int rr = 0; rr < 32; ++rr) {
            float va = Sr[rr][a];
#pragma unroll
            for (int j = 0; j < 16; ++j) acc[j] += va * Sr[rr][bq * 16 + j];
        }
        __syncthreads();
    }
#pragma unroll
    for (int j = 0; j < 16; ++j) atomicAdd(&SS[a * 64 + bq * 16 + j], acc[j]);
}

// single block: reduce partials, compute losses, write d_out[N*16]
__global__ void scalars_kernel(const float* __restrict__ cutp, const float* __restrict__ dtp,
                               const float* __restrict__ SS, float* __restrict__ out) {
    __shared__ float red[256];
    int t = threadIdx.x;
    float c = 0.f;
    for (int i = t; i < CUT_BLOCKS; i += 256) c += cutp[i];
    red[t] = c; __syncthreads();
    for (int s = 128; s; s >>= 1) { if (t < s) red[t] += red[t + s]; __syncthreads(); }
    float cut = red[0]; __syncthreads();

    float d = 0.f;
    for (int i = t; i < SM_BLOCKS; i += 256) d += dtp[i];
    red[t] = d; __syncthreads();
    for (int s = 128; s; s >>= 1) { if (t < s) red[t] += red[t + s]; __syncthreads(); }
    float dterm = red[0]; __syncthreads();

    float ss[16];
    float sq = 0.f;
#pragma unroll
    for (int j = 0; j < 16; ++j) { ss[j] = SS[t * 16 + j]; sq += ss[j] * ss[j]; }
    red[t] = sq; __syncthreads();
    for (int s = 128; s; s >>= 1) { if (t < s) red[t] += red[t + s]; __syncthreads(); }
    float nrm = sqrtf(red[0]); __syncthreads();

    float osq = 0.f;
#pragma unroll
    for (int j = 0; j < 16; ++j) {
        int idx = t * 16 + j;
        float v = ss[j] / nrm - ((idx % 65 == 0) ? 0.125f : 0.f);
        osq += v * v;
    }
    red[t] = osq; __syncthreads();
    for (int s = 128; s; s >>= 1) { if (t < s) red[t] += red[t + s]; __syncthreads(); }
    if (t == 0) {
        float loss = -(cut / dterm) + sqrtf(red[0]);
        out[(long long)N_NODES * OUT_C] = loss;
    }
}

// logits[r] = x[r]·Weff[0:128] + S[r]·Weff[128:192] + beff ; log_softmax; store
__global__ void out_kernel(const float* __restrict__ x, const float* __restrict__ S,
                           const float* __restrict__ Weff, const float* __restrict__ beff,
                           float* __restrict__ out) {
    __shared__ float ch[256][33];
    int t = threadIdx.x;
    long long r0 = (long long)blockIdx.x * 256;
    int r = (int)r0 + t;
    float p[16];
#pragma unroll
    for (int o = 0; o < 16; ++o) p[o] = beff[o];

    for (int cki = 0; cki < 4; ++cki) {
        for (int i = t; i < 256 * 32; i += 256) {
            int rr = i >> 5, kk = i & 31;
            int rg = (int)r0 + rr;
            ch[rr][kk] = (rg < N_NODES) ? x[(long long)rg * IN_C + cki * 32 + kk] : 0.f;
        }
        __syncthreads();
#pragma unroll 8
        for (int kk = 0; kk < 32; ++kk) {
            float xk = ch[t][kk];
            int kg = cki * 32 + kk;
#pragma unroll
            for (int o = 0; o < 16; ++o) p[o] += xk * Weff[kg * 16 + o];
        }
        __syncthreads();
    }
    for (int sck = 0; sck < 2; ++sck) {
        for (int i = t; i < 256 * 32; i += 256) {
            int rr = i >> 5, kk = i & 31;
            int rg = (int)r0 + rr;
            ch[rr][kk] = (rg < N_NODES) ? S[(long long)rg * 64 + sck * 32 + kk] : 0.f;
        }
        __syncthreads();
#pragma unroll 8
        for (int kk = 0; kk < 32; ++kk) {
            float xk = ch[t][kk];
            int kg = 128 + sck * 32 + kk;
#pragma unroll
            for (int o = 0; o < 16; ++o) p[o] += xk * Weff[kg * 16 + o];
        }
        __syncthreads();
    }

    if (r < N_NODES) {
        float m = p[0];
#pragma unroll
        for (int o = 1; o < 16; ++o) m = fmaxf(m, p[o]);
        float s = 0.f;
#pragma unroll
        for (int o = 0; o < 16; ++o) s += __expf(p[o] - m);
        float lse = m + logf(s);
        float4* o4 = (float4*)(out + (long long)r * 16);
#pragma unroll
        for (int q = 0; q < 4; ++q)
            o4[q] = make_float4(p[q * 4 + 0] - lse, p[q * 4 + 1] - lse,
                                p[q * 4 + 2] - lse, p[q * 4 + 3] - lse);
    }
}

extern "C" void kernel_launch(void* const* d_in, const int* in_sizes, int n_in,
                              void* d_out, int out_size, void* d_ws, size_t ws_size,
                              hipStream_t stream) {
    const float* x     = (const float*)d_in[0];
    const int*   ei    = (const int*)d_in[1];
    const float* MLPW  = (const float*)d_in[2];
    const float* MLPb  = (const float*)d_in[3];
    const float* mlpxW = (const float*)d_in[4];
    const float* mlpxb = (const float*)d_in[5];
    const float* finW  = (const float*)d_in[6];
    const float* finb  = (const float*)d_in[7];
    float* out = (float*)d_out;
    float* ws  = (float*)d_ws;

    float* WT   = ws;                                   // N*64
    float* xA   = WT + (size_t)N_NODES * 64;            // N*64
    float* S    = xA + (size_t)N_NODES * 64;            // N*64
    float* deg  = S + (size_t)N_NODES * 64;             // N
    float* SS   = deg + N_NODES;                        // 4096
    float* Weff = SS + 4096;                            // 192*16
    float* beff = Weff + 192 * 16;                      // 16
    float* cutp = beff + 16;                            // CUT_BLOCKS
    float* dtp  = cutp + CUT_BLOCKS;                    // SM_BLOCKS

    hipLaunchKernelGGL(prep_weff, dim3(13), dim3(256), 0, stream,
                       mlpxW, mlpxb, finW, finb, Weff, beff);
    hipLaunchKernelGGL(transpose_w, dim3(TRANS_BLOCKS), dim3(256), 0, stream, MLPW, WT);
    hipLaunchKernelGGL(init_ws, dim3(2048), dim3(256), 0, stream, xA, deg, SS, MLPb);
    hipLaunchKernelGGL(scatter_edges, dim3(SCATTER_BLOCKS), dim3(256), 0, stream,
                       ei, WT, xA, deg);
    hipLaunchKernelGGL(softmax_rows, dim3(SM_BLOCKS), dim3(256), 0, stream, xA, deg, S, dtp);
    hipLaunchKernelGGL(cut_edges, dim3(CUT_BLOCKS), dim3(256), 0, stream, ei, S, cutp);
    hipLaunchKernelGGL(ss_kernel, dim3(SS_BLOCKS), dim3(256), 0, stream, S, SS);
    hipLaunchKernelGGL(scalars_kernel, dim3(1), dim3(256), 0, stream, cutp, dtp, SS, out);
    hipLaunchKernelGGL(out_kernel, dim3(OUT_BLOCKS), dim3(256), 0, stream, x, S, Weff, beff, out);
}

// Round 2
// 810.121 us; speedup vs baseline: 1.1982x; 1.1982x over previous
//
#include <hip/hip_runtime.h>
#include <math.h>

#define N_NODES 100000
#define N_EDGES 1600000
#define IN_C    128
#define HID     256
#define KEIG    64
#define OUT_C   16

#define TRANS_BLOCKS   ((N_NODES + 63) / 64)
#define HIST_BLOCKS    1024
#define FILL_BLOCKS    1024
#define GATHER_BLOCKS  2048
#define CUT_BLOCKS     2048
#define SS_BLOCKS      256
#define OUT_BLOCKS     ((N_NODES + 255) / 256)
#define SCAN_THREADS   1024
#define SCAN_CHUNK     ((N_NODES + SCAN_THREADS - 1) / SCAN_THREADS)

__device__ __forceinline__ float wave_sum(float v) {
#pragma unroll
    for (int m = 32; m; m >>= 1) v += __shfl_xor(v, m, 64);
    return v;
}
__device__ __forceinline__ float wave_max(float v) {
#pragma unroll
    for (int m = 32; m; m >>= 1) v = fmaxf(v, __shfl_xor(v, m, 64));
    return v;
}

// ---------------- small precompute ----------------
__global__ void prep_weff(const float* __restrict__ mlpxW, const float* __restrict__ mlpxb,
                          const float* __restrict__ finW, const float* __restrict__ finb,
                          float* __restrict__ Weff, float* __restrict__ beff) {
    int t = blockIdx.x * blockDim.x + threadIdx.x;
    const int NW = (IN_C + KEIG) * OUT_C;
    if (t < NW) {
        int k = t >> 4, o = t & 15;
        float acc;
        if (k < IN_C) {
            acc = 0.f;
            for (int c = 0; c < HID; ++c)
                acc += mlpxW[c * IN_C + k] * finW[o * (HID + KEIG) + c];
        } else {
            acc = finW[o * (HID + KEIG) + HID + (k - IN_C)];
        }
        Weff[k * OUT_C + o] = acc;
    }
    int tb = t - NW;
    if (tb >= 0 && tb < OUT_C) {
        float acc = finb[tb];
        for (int c = 0; c < HID; ++c) acc += mlpxb[c] * finW[tb * (HID + KEIG) + c];
        beff[tb] = acc;
    }
}

// MLP_W [64, N] -> WT [N, 64]
__global__ void transpose_w(const float* __restrict__ W, float* __restrict__ WT) {
    __shared__ float tile[64][65];
    int n0 = blockIdx.x * 64;
    int t = threadIdx.x;
    int tn = t & 63, tq = t >> 6;
#pragma unroll
    for (int kk = 0; kk < 16; ++kk) {
        int k = tq * 16 + kk;
        int n = n0 + tn;
        tile[k][tn] = (n < N_NODES) ? W[(long long)k * N_NODES + n] : 0.f;
    }
    __syncthreads();
    int tk = t & 63;
#pragma unroll
    for (int ii = 0; ii < 16; ++ii) {
        int n = n0 + tq * 16 + ii;
        if (n < N_NODES) WT[(long long)n * 64 + tk] = tile[tk][tq * 16 + ii];
    }
}

// ---------------- CSR build ----------------
__global__ void zero_counts(int* __restrict__ counts) {
    int t = blockIdx.x * blockDim.x + threadIdx.x;
    if (t < N_NODES) counts[t] = 0;
}

__global__ void hist_kernel(const int* __restrict__ ei, int* __restrict__ counts) {
    int t = blockIdx.x * blockDim.x + threadIdx.x;
    int stride = gridDim.x * blockDim.x;
    for (int e = t; e < N_EDGES; e += stride)
        atomicAdd(&counts[ei[N_EDGES + e]], 1);
}

// single block: exclusive prefix over counts -> offsets (+cursor copy)
__global__ void scan_kernel(const int* __restrict__ counts, int* __restrict__ offsets,
                            int* __restrict__ cursor) {
    __shared__ int part[SCAN_THREADS];
    int t = threadIdx.x;
    int lo = t * SCAN_CHUNK, hi = min(lo + SCAN_CHUNK, N_NODES);
    int s = 0;
    for (int i = lo; i < hi; ++i) s += counts[i];
    part[t] = s;
    __syncthreads();
    for (int d = 1; d < SCAN_THREADS; d <<= 1) {
        int v = (t >= d) ? part[t - d] : 0;
        __syncthreads();
        part[t] += v;
        __syncthreads();
    }
    int run = (t == 0) ? 0 : part[t - 1];
    for (int i = lo; i < hi; ++i) {
        offsets[i] = run;
        cursor[i] = run;
        run += counts[i];
    }
    if (t == SCAN_THREADS - 1) offsets[N_NODES] = run;
}

__global__ void fill_csr(const int* __restrict__ ei, int* __restrict__ cursor,
                         int* __restrict__ csr_row) {
    int t = blockIdx.x * blockDim.x + threadIdx.x;
    int stride = gridDim.x * blockDim.x;
    for (int e = t; e < N_EDGES; e += stride) {
        int r = ei[e];
        int c = ei[N_EDGES + e];
        int p = atomicAdd(&cursor[c], 1);
        csr_row[p] = r;
    }
}

// ---------------- pass 1: gather + bias + softmax + deg_term ----------------
__global__ void gather_softmax(const int* __restrict__ offsets, const int* __restrict__ csr_row,
                               const float* __restrict__ WT, const float* __restrict__ MLPb,
                               float* __restrict__ S, float* __restrict__ dtp) {
    int lane = threadIdx.x & 63;
    int wib = threadIdx.x >> 6;
    int gw = (blockIdx.x * blockDim.x + threadIdx.x) >> 6;
    int nw = (gridDim.x * blockDim.x) >> 6;
    float bias = MLPb[lane];
    float dacc = 0.f;
    for (int n = gw; n < N_NODES; n += nw) {
        int s0 = offsets[n], s1 = offsets[n + 1];
        float acc = bias;
        for (int base = s0; base < s1; base += 64) {
            int cnt = min(64, s1 - base);
            int rv = (lane < cnt) ? csr_row[base + lane] : 0;
            int j = 0;
            for (; j + 3 < cnt; j += 4) {
                int r0 = __shfl(rv, j, 64);
                int r1 = __shfl(rv, j + 1, 64);
                int r2 = __shfl(rv, j + 2, 64);
                int r3 = __shfl(rv, j + 3, 64);
                float v0 = WT[(long long)r0 * 64 + lane];
                float v1 = WT[(long long)r1 * 64 + lane];
                float v2 = WT[(long long)r2 * 64 + lane];
                float v3 = WT[(long long)r3 * 64 + lane];
                acc += (v0 + v1) + (v2 + v3);
            }
            for (; j < cnt; ++j) {
                int r = __shfl(rv, j, 64);
                acc += WT[(long long)r * 64 + lane];
            }
        }
        float m = wave_max(acc);
        float e = __expf(acc - m);
        float sm = wave_sum(e);
        float sv = e / sm;
        S[(long long)n * 64 + lane] = sv;
        dacc += (float)(s1 - s0) * sv * sv;
    }
    dacc = wave_sum(dacc);
    __shared__ float red[4];
    if (lane == 0) red[wib] = dacc;
    __syncthreads();
    if (threadIdx.x == 0) dtp[blockIdx.x] = red[0] + red[1] + red[2] + red[3];
}

// ---------------- pass 2: cut = sum_c S[c] . (sum_{e in c} S[row_e]) ----------------
__global__ void cut_csr(const int* __restrict__ offsets, const int* __restrict__ csr_row,
                        const float* __restrict__ S, float* __restrict__ cutp) {
    int lane = threadIdx.x & 63;
    int wib = threadIdx.x >> 6;
    int gw = (blockIdx.x * blockDim.x + threadIdx.x) >> 6;
    int nw = (gridDim.x * blockDim.x) >> 6;
    float acc = 0.f;
    for (int n = gw; n < N_NODES; n += nw) {
        float sc = S[(long long)n * 64 + lane];
        int s0 = offsets[n], s1 = offsets[n + 1];
        float g = 0.f;
        for (int base = s0; base < s1; base += 64) {
            int cnt = min(64, s1 - base);
            int rv = (lane < cnt) ? csr_row[base + lane] : 0;
            int j = 0;
            for (; j + 3 < cnt; j += 4) {
                int r0 = __shfl(rv, j, 64);
                int r1 = __shfl(rv, j + 1, 64);
                int r2 = __shfl(rv, j + 2, 64);
                int r3 = __shfl(rv, j + 3, 64);
                float v0 = S[(long long)r0 * 64 + lane];
                float v1 = S[(long long)r1 * 64 + lane];
                float v2 = S[(long long)r2 * 64 + lane];
                float v3 = S[(long long)r3 * 64 + lane];
                g += (v0 + v1) + (v2 + v3);
            }
            for (; j < cnt; ++j) {
                int r = __shfl(rv, j, 64);
                g += S[(long long)r * 64 + lane];
            }
        }
        acc += sc * g;
    }
    acc = wave_sum(acc);
    __shared__ float red[4];
    if (lane == 0) red[wib] = acc;
    __syncthreads();
    if (threadIdx.x == 0) cutp[blockIdx.x] = red[0] + red[1] + red[2] + red[3];
}

// ---------------- SS = S^T S, per-block partials ----------------
__global__ void ss_kernel(const float* __restrict__ S, float* __restrict__ ssp) {
    __shared__ float Sr[32][65];
    int t = threadIdx.x;
    int a = t & 63, bq = t >> 6;
    float acc[16];
#pragma unroll
    for (int j = 0; j < 16; ++j) acc[j] = 0.f;
    for (int base = blockIdx.x * 32; base < N_NODES; base += gridDim.x * 32) {
        int nr = min(32, N_NODES - base);
        for (int i = t; i < 32 * 64; i += 256) {
            int rr = i >> 6, cc = i & 63;
            Sr[rr][cc] = (rr < nr) ? S[(long long)(base + rr) * 64 + cc] : 0.f;
        }
        __syncthreads();
        for (int rr = 0; rr < 32; ++rr) {
            float va = Sr[rr][a];
#pragma unroll
            for (int j = 0; j < 16; ++j) acc[j] += va * Sr[rr][bq * 16 + j];
        }
        __syncthreads();
    }
    float* dst = ssp + (size_t)blockIdx.x * 4096;
#pragma unroll
    for (int j = 0; j < 16; ++j) dst[a * 64 + bq * 16 + j] = acc[j];
}

__global__ void reduce_ss(const float* __restrict__ ssp, float* __restrict__ SS) {
    int e = blockIdx.x * blockDim.x + threadIdx.x; // 0..4095
    float s = 0.f;
    for (int p = 0; p < SS_BLOCKS; ++p) s += ssp[(size_t)p * 4096 + e];
    SS[e] = s;
}

// ---------------- scalar losses ----------------
__global__ void scalars_kernel(const float* __restrict__ cutp, const float* __restrict__ dtp,
                               const float* __restrict__ SS, float* __restrict__ out) {
    __shared__ float red[256];
    int t = threadIdx.x;
    float c = 0.f;
    for (int i = t; i < CUT_BLOCKS; i += 256) c += cutp[i];
    red[t] = c; __syncthreads();
    for (int s = 128; s; s >>= 1) { if (t < s) red[t] += red[t + s]; __syncthreads(); }
    float cut = red[0]; __syncthreads();

    float d = 0.f;
    for (int i = t; i < GATHER_BLOCKS; i += 256) d += dtp[i];
    red[t] = d; __syncthreads();
    for (int s = 128; s; s >>= 1) { if (t < s) red[t] += red[t + s]; __syncthreads(); }
    float dterm = red[0]; __syncthreads();

    float ss[16];
    float sq = 0.f;
#pragma unroll
    for (int j = 0; j < 16; ++j) { ss[j] = SS[t * 16 + j]; sq += ss[j] * ss[j]; }
    red[t] = sq; __syncthreads();
    for (int s = 128; s; s >>= 1) { if (t < s) red[t] += red[t + s]; __syncthreads(); }
    float nrm = sqrtf(red[0]); __syncthreads();

    float osq = 0.f;
#pragma unroll
    for (int j = 0; j < 16; ++j) {
        int idx = t * 16 + j;
        float v = ss[j] / nrm - ((idx % 65 == 0) ? 0.125f : 0.f);
        osq += v * v;
    }
    red[t] = osq; __syncthreads();
    for (int s = 128; s; s >>= 1) { if (t < s) red[t] += red[t + s]; __syncthreads(); }
    if (t == 0) {
        float loss = -(cut / dterm) + sqrtf(red[0]);
        out[(long long)N_NODES * OUT_C] = loss;
    }
}

// ---------------- output: logits + log_softmax ----------------
__global__ void out_kernel(const float* __restrict__ x, const float* __restrict__ S,
                           const float* __restrict__ Weff, const float* __restrict__ beff,
                           float* __restrict__ out) {
    __shared__ float ch[256][33];
    int t = threadIdx.x;
    long long r0 = (long long)blockIdx.x * 256;
    int r = (int)r0 + t;
    float p[16];
#pragma unroll
    for (int o = 0; o < 16; ++o) p[o] = beff[o];

    for (int cki = 0; cki < 4; ++cki) {
        for (int i = t; i < 256 * 32; i += 256) {
            int rr = i >> 5, kk = i & 31;
            int rg = (int)r0 + rr;
            ch[rr][kk] = (rg < N_NODES) ? x[(long long)rg * IN_C + cki * 32 + kk] : 0.f;
        }
        __syncthreads();
#pragma unroll 8
        for (int kk = 0; kk < 32; ++kk) {
            float xk = ch[t][kk];
            int kg = cki * 32 + kk;
#pragma unroll
            for (int o = 0; o < 16; ++o) p[o] += xk * Weff[kg * 16 + o];
        }
        __syncthreads();
    }
    for (int sck = 0; sck < 2; ++sck) {
        for (int i = t; i < 256 * 32; i += 256) {
            int rr = i >> 5, kk = i & 31;
            int rg = (int)r0 + rr;
            ch[rr][kk] = (rg < N_NODES) ? S[(long long)rg * 64 + sck * 32 + kk] : 0.f;
        }
        __syncthreads();
#pragma unroll 8
        for (int kk = 0; kk < 32; ++kk) {
            float xk = ch[t][kk];
            int kg = 128 + sck * 32 + kk;
#pragma unroll
            for (int o = 0; o < 16; ++o) p[o] += xk * Weff[kg * 16 + o];
        }
        __syncthreads();
    }

    if (r < N_NODES) {
        float m = p[0];
#pragma unroll
        for (int o = 1; o < 16; ++o) m = fmaxf(m, p[o]);
        float s = 0.f;
#pragma unroll
        for (int o = 0; o < 16; ++o) s += __expf(p[o] - m);
        float lse = m + logf(s);
        float4* o4 = (float4*)(out + (long long)r * 16);
#pragma unroll
        for (int q = 0; q < 4; ++q)
            o4[q] = make_float4(p[q * 4 + 0] - lse, p[q * 4 + 1] - lse,
                                p[q * 4 + 2] - lse, p[q * 4 + 3] - lse);
    }
}

extern "C" void kernel_launch(void* const* d_in, const int* in_sizes, int n_in,
                              void* d_out, int out_size, void* d_ws, size_t ws_size,
                              hipStream_t stream) {
    const float* x     = (const float*)d_in[0];
    const int*   ei    = (const int*)d_in[1];
    const float* MLPW  = (const float*)d_in[2];
    const float* MLPb  = (const float*)d_in[3];
    const float* mlpxW = (const float*)d_in[4];
    const float* mlpxb = (const float*)d_in[5];
    const float* finW  = (const float*)d_in[6];
    const float* finb  = (const float*)d_in[7];
    float* out = (float*)d_out;
    float* ws  = (float*)d_ws;

    float* WT      = ws;                                    // N*64 f
    float* S       = WT + (size_t)N_NODES * 64;             // N*64 f
    float* ssp     = S + (size_t)N_NODES * 64;              // 256*4096 f
    float* SS      = ssp + (size_t)SS_BLOCKS * 4096;        // 4096 f
    float* Weff    = SS + 4096;                             // 3072 f
    float* beff    = Weff + 192 * 16;                       // 16 f
    float* cutp    = beff + 16;                             // CUT_BLOCKS f
    float* dtp     = cutp + CUT_BLOCKS;                     // GATHER_BLOCKS f
    int*   counts  = (int*)(dtp + GATHER_BLOCKS);           // N i
    int*   offsets = counts + N_NODES;                      // N+1 i
    int*   cursor  = offsets + N_NODES + 1;                 // N i
    int*   csr_row = cursor + N_NODES;                      // E i

    hipLaunchKernelGGL(prep_weff, dim3(13), dim3(256), 0, stream,
                       mlpxW, mlpxb, finW, finb, Weff, beff);
    hipLaunchKernelGGL(transpose_w, dim3(TRANS_BLOCKS), dim3(256), 0, stream, MLPW, WT);
    hipLaunchKernelGGL(zero_counts, dim3((N_NODES + 255) / 256), dim3(256), 0, stream, counts);
    hipLaunchKernelGGL(hist_kernel, dim3(HIST_BLOCKS), dim3(256), 0, stream, ei, counts);
    hipLaunchKernelGGL(scan_kernel, dim3(1), dim3(SCAN_THREADS), 0, stream,
                       counts, offsets, cursor);
    hipLaunchKernelGGL(fill_csr, dim3(FILL_BLOCKS), dim3(256), 0, stream, ei, cursor, csr_row);
    hipLaunchKernelGGL(gather_softmax, dim3(GATHER_BLOCKS), dim3(256), 0, stream,
                       offsets, csr_row, WT, MLPb, S, dtp);
    hipLaunchKernelGGL(cut_csr, dim3(CUT_BLOCKS), dim3(256), 0, stream,
                       offsets, csr_row, S, cutp);
    hipLaunchKernelGGL(ss_kernel, dim3(SS_BLOCKS), dim3(256), 0, stream, S, ssp);
    hipLaunchKernelGGL(reduce_ss, dim3(16), dim3(256), 0, stream, ssp, SS);
    hipLaunchKernelGGL(scalars_kernel, dim3(1), dim3(256), 0, stream, cutp, dtp, SS, out);
    hipLaunchKernelGGL(out_kernel, dim3(OUT_BLOCKS), dim3(256), 0, stream, x, S, Weff, beff, out);
}

// Round 3
// 611.007 us; speedup vs baseline: 1.5887x; 1.3259x over previous
//
#include <hip/hip_runtime.h>
#include <math.h>

#define N_NODES 100000
#define N_EDGES 1600000
#define IN_C    128
#define HID     256
#define KEIG    64
#define OUT_C   16

#define TRANS_BLOCKS   ((N_NODES + 63) / 64)
#define HIST_BLOCKS    1024
#define FILL_BLOCKS    1024
#define GATHER_BLOCKS  2048
#define CUT_BLOCKS     2048
#define SS_BLOCKS      256
#define OUT_BLOCKS     ((N_NODES + 255) / 256)
#define NSCAN_BLOCKS   ((N_NODES + 255) / 256)   // 391

__device__ __forceinline__ float wave_sum(float v) {
#pragma unroll
    for (int m = 32; m; m >>= 1) v += __shfl_xor(v, m, 64);
    return v;
}
__device__ __forceinline__ float wave_max(float v) {
#pragma unroll
    for (int m = 32; m; m >>= 1) v = fmaxf(v, __shfl_xor(v, m, 64));
    return v;
}

// ---------------- small precompute ----------------
__global__ void prep_weff(const float* __restrict__ mlpxW, const float* __restrict__ mlpxb,
                          const float* __restrict__ finW, const float* __restrict__ finb,
                          float* __restrict__ Weff, float* __restrict__ beff) {
    int t = blockIdx.x * blockDim.x + threadIdx.x;
    const int NW = (IN_C + KEIG) * OUT_C;
    if (t < NW) {
        int k = t >> 4, o = t & 15;
        float acc;
        if (k < IN_C) {
            acc = 0.f;
            for (int c = 0; c < HID; ++c)
                acc += mlpxW[c * IN_C + k] * finW[o * (HID + KEIG) + c];
        } else {
            acc = finW[o * (HID + KEIG) + HID + (k - IN_C)];
        }
        Weff[k * OUT_C + o] = acc;
    }
    int tb = t - NW;
    if (tb >= 0 && tb < OUT_C) {
        float acc = finb[tb];
        for (int c = 0; c < HID; ++c) acc += mlpxb[c] * finW[tb * (HID + KEIG) + c];
        beff[tb] = acc;
    }
}

// MLP_W [64, N] -> WT [N, 64]
__global__ void transpose_w(const float* __restrict__ W, float* __restrict__ WT) {
    __shared__ float tile[64][65];
    int n0 = blockIdx.x * 64;
    int t = threadIdx.x;
    int tn = t & 63, tq = t >> 6;
#pragma unroll
    for (int kk = 0; kk < 16; ++kk) {
        int k = tq * 16 + kk;
        int n = n0 + tn;
        tile[k][tn] = (n < N_NODES) ? W[(long long)k * N_NODES + n] : 0.f;
    }
    __syncthreads();
    int tk = t & 63;
#pragma unroll
    for (int ii = 0; ii < 16; ++ii) {
        int n = n0 + tq * 16 + ii;
        if (n < N_NODES) WT[(long long)n * 64 + tk] = tile[tk][tq * 16 + ii];
    }
}

// ---------------- CSR build ----------------
__global__ void zero_counts(int* __restrict__ counts) {
    int t = blockIdx.x * blockDim.x + threadIdx.x;
    if (t < N_NODES) counts[t] = 0;
}

__global__ void hist_kernel(const int* __restrict__ ei, int* __restrict__ counts) {
    int t = blockIdx.x * blockDim.x + threadIdx.x;
    int stride = gridDim.x * blockDim.x;
    for (int e = t; e < N_EDGES; e += stride)
        atomicAdd(&counts[ei[N_EDGES + e]], 1);
}

// level 1: per-block sums of 256 counts
__global__ void scan_reduce(const int* __restrict__ counts, int* __restrict__ bsum) {
    __shared__ int red[256];
    int t = threadIdx.x;
    int i = blockIdx.x * 256 + t;
    red[t] = (i < N_NODES) ? counts[i] : 0;
    __syncthreads();
    for (int s = 128; s; s >>= 1) { if (t < s) red[t] += red[t + s]; __syncthreads(); }
    if (t == 0) bsum[blockIdx.x] = red[0];
}

// level 2: single block, exclusive scan of NSCAN_BLOCKS block sums
__global__ void scan_toplevel(const int* __restrict__ bsum, int* __restrict__ boff) {
    __shared__ int sh[512];
    int t = threadIdx.x;
    int v = (t < NSCAN_BLOCKS) ? bsum[t] : 0;
    sh[t] = v;
    __syncthreads();
    for (int d = 1; d < 512; d <<= 1) {
        int u = (t >= d) ? sh[t - d] : 0;
        __syncthreads();
        sh[t] += u;
        __syncthreads();
    }
    if (t < NSCAN_BLOCKS) boff[t] = sh[t] - v;   // exclusive
}

// level 3: in-block exclusive scan + block offset -> offsets, cursor
__global__ void scan_apply(const int* __restrict__ counts, const int* __restrict__ boff,
                           int* __restrict__ offsets, int* __restrict__ cursor) {
    __shared__ int sh[256];
    int t = threadIdx.x;
    int i = blockIdx.x * 256 + t;
    int v = (i < N_NODES) ? counts[i] : 0;
    sh[t] = v;
    __syncthreads();
    for (int d = 1; d < 256; d <<= 1) {
        int u = (t >= d) ? sh[t - d] : 0;
        __syncthreads();
        sh[t] += u;
        __syncthreads();
    }
    if (i < N_NODES) {
        int off = boff[blockIdx.x] + sh[t] - v;
        offsets[i] = off;
        cursor[i] = off;
    }
    if (i == 0) offsets[N_NODES] = N_EDGES;  // total degree == E (all cols in range)
}

__global__ void fill_csr(const int* __restrict__ ei, int* __restrict__ cursor,
                         int* __restrict__ csr_row) {
    int t = blockIdx.x * blockDim.x + threadIdx.x;
    int stride = gridDim.x * blockDim.x;
    for (int e = t; e < N_EDGES; e += stride) {
        int r = ei[e];
        int c = ei[N_EDGES + e];
        int p = atomicAdd(&cursor[c], 1);
        csr_row[p] = r;
    }
}

// ---------------- pass 1: gather + bias + softmax + deg_term ----------------
__global__ void gather_softmax(const int* __restrict__ offsets, const int* __restrict__ csr_row,
                               const float* __restrict__ WT, const float* __restrict__ MLPb,
                               float* __restrict__ S, float* __restrict__ dtp) {
    int lane = threadIdx.x & 63;
    int wib = threadIdx.x >> 6;
    int gw = (blockIdx.x * blockDim.x + threadIdx.x) >> 6;
    int nw = (gridDim.x * blockDim.x) >> 6;
    float bias = MLPb[lane];
    float dacc = 0.f;
    for (int n = gw; n < N_NODES; n += nw) {
        int s0 = offsets[n], s1 = offsets[n + 1];
        float acc = bias;
        for (int base = s0; base < s1; base += 64) {
            int cnt = min(64, s1 - base);
            int rv = (lane < cnt) ? csr_row[base + lane] : 0;
            int j = 0;
            for (; j + 3 < cnt; j += 4) {
                int r0 = __shfl(rv, j, 64);
                int r1 = __shfl(rv, j + 1, 64);
                int r2 = __shfl(rv, j + 2, 64);
                int r3 = __shfl(rv, j + 3, 64);
                float v0 = WT[(long long)r0 * 64 + lane];
                float v1 = WT[(long long)r1 * 64 + lane];
                float v2 = WT[(long long)r2 * 64 + lane];
                float v3 = WT[(long long)r3 * 64 + lane];
                acc += (v0 + v1) + (v2 + v3);
            }
            for (; j < cnt; ++j) {
                int r = __shfl(rv, j, 64);
                acc += WT[(long long)r * 64 + lane];
            }
        }
        float m = wave_max(acc);
        float e = __expf(acc - m);
        float sm = wave_sum(e);
        float sv = e / sm;
        S[(long long)n * 64 + lane] = sv;
        dacc += (float)(s1 - s0) * sv * sv;
    }
    dacc = wave_sum(dacc);
    __shared__ float red[4];
    if (lane == 0) red[wib] = dacc;
    __syncthreads();
    if (threadIdx.x == 0) dtp[blockIdx.x] = red[0] + red[1] + red[2] + red[3];
}

// ---------------- pass 2: cut = sum_c S[c] . (sum_{e in c} S[row_e]) ----------------
__global__ void cut_csr(const int* __restrict__ offsets, const int* __restrict__ csr_row,
                        const float* __restrict__ S, float* __restrict__ cutp) {
    int lane = threadIdx.x & 63;
    int wib = threadIdx.x >> 6;
    int gw = (blockIdx.x * blockDim.x + threadIdx.x) >> 6;
    int nw = (gridDim.x * blockDim.x) >> 6;
    float acc = 0.f;
    for (int n = gw; n < N_NODES; n += nw) {
        float sc = S[(long long)n * 64 + lane];
        int s0 = offsets[n], s1 = offsets[n + 1];
        float g = 0.f;
        for (int base = s0; base < s1; base += 64) {
            int cnt = min(64, s1 - base);
            int rv = (lane < cnt) ? csr_row[base + lane] : 0;
            int j = 0;
            for (; j + 3 < cnt; j += 4) {
                int r0 = __shfl(rv, j, 64);
                int r1 = __shfl(rv, j + 1, 64);
                int r2 = __shfl(rv, j + 2, 64);
                int r3 = __shfl(rv, j + 3, 64);
                float v0 = S[(long long)r0 * 64 + lane];
                float v1 = S[(long long)r1 * 64 + lane];
                float v2 = S[(long long)r2 * 64 + lane];
                float v3 = S[(long long)r3 * 64 + lane];
                g += (v0 + v1) + (v2 + v3);
            }
            for (; j < cnt; ++j) {
                int r = __shfl(rv, j, 64);
                g += S[(long long)r * 64 + lane];
            }
        }
        acc += sc * g;
    }
    acc = wave_sum(acc);
    __shared__ float red[4];
    if (lane == 0) red[wib] = acc;
    __syncthreads();
    if (threadIdx.x == 0) cutp[blockIdx.x] = red[0] + red[1] + red[2] + red[3];
}

// ---------------- SS = S^T S, per-block partials ----------------
__global__ void ss_kernel(const float* __restrict__ S, float* __restrict__ ssp) {
    __shared__ float Sr[32][65];
    int t = threadIdx.x;
    int a = t & 63, bq = t >> 6;
    float acc[16];
#pragma unroll
    for (int j = 0; j < 16; ++j) acc[j] = 0.f;
    for (int base = blockIdx.x * 32; base < N_NODES; base += gridDim.x * 32) {
        int nr = min(32, N_NODES - base);
        for (int i = t; i < 32 * 64; i += 256) {
            int rr = i >> 6, cc = i & 63;
            Sr[rr][cc] = (rr < nr) ? S[(long long)(base + rr) * 64 + cc] : 0.f;
        }
        __syncthreads();
        for (int rr = 0; rr < 32; ++rr) {
            float va = Sr[rr][a];
#pragma unroll
            for (int j = 0; j < 16; ++j) acc[j] += va * Sr[rr][bq * 16 + j];
        }
        __syncthreads();
    }
    float* dst = ssp + (size_t)blockIdx.x * 4096;
#pragma unroll
    for (int j = 0; j < 16; ++j) dst[a * 64 + bq * 16 + j] = acc[j];
}

__global__ void reduce_ss(const float* __restrict__ ssp, float* __restrict__ SS) {
    int e = blockIdx.x * blockDim.x + threadIdx.x; // 0..4095
    float s = 0.f;
    for (int p = 0; p < SS_BLOCKS; ++p) s += ssp[(size_t)p * 4096 + e];
    SS[e] = s;
}

// ---------------- scalar losses ----------------
__global__ void scalars_kernel(const float* __restrict__ cutp, const float* __restrict__ dtp,
                               const float* __restrict__ SS, float* __restrict__ out) {
    __shared__ float red[256];
    int t = threadIdx.x;
    float c = 0.f;
    for (int i = t; i < CUT_BLOCKS; i += 256) c += cutp[i];
    red[t] = c; __syncthreads();
    for (int s = 128; s; s >>= 1) { if (t < s) red[t] += red[t + s]; __syncthreads(); }
    float cut = red[0]; __syncthreads();

    float d = 0.f;
    for (int i = t; i < GATHER_BLOCKS; i += 256) d += dtp[i];
    red[t] = d; __syncthreads();
    for (int s = 128; s; s >>= 1) { if (t < s) red[t] += red[t + s]; __syncthreads(); }
    float dterm = red[0]; __syncthreads();

    float ss[16];
    float sq = 0.f;
#pragma unroll
    for (int j = 0; j < 16; ++j) { ss[j] = SS[t * 16 + j]; sq += ss[j] * ss[j]; }
    red[t] = sq; __syncthreads();
    for (int s = 128; s; s >>= 1) { if (t < s) red[t] += red[t + s]; __syncthreads(); }
    float nrm = sqrtf(red[0]); __syncthreads();

    float osq = 0.f;
#pragma unroll
    for (int j = 0; j < 16; ++j) {
        int idx = t * 16 + j;
        float v = ss[j] / nrm - ((idx % 65 == 0) ? 0.125f : 0.f);
        osq += v * v;
    }
    red[t] = osq; __syncthreads();
    for (int s = 128; s; s >>= 1) { if (t < s) red[t] += red[t + s]; __syncthreads(); }
    if (t == 0) {
        float loss = -(cut / dterm) + sqrtf(red[0]);
        out[(long long)N_NODES * OUT_C] = loss;
    }
}

// ---------------- output: logits + log_softmax ----------------
__global__ void out_kernel(const float* __restrict__ x, const float* __restrict__ S,
                           const float* __restrict__ Weff, const float* __restrict__ beff,
                           float* __restrict__ out) {
    __shared__ float ch[256][33];
    int t = threadIdx.x;
    long long r0 = (long long)blockIdx.x * 256;
    int r = (int)r0 + t;
    float p[16];
#pragma unroll
    for (int o = 0; o < 16; ++o) p[o] = beff[o];

    for (int cki = 0; cki < 4; ++cki) {
        for (int i = t; i < 256 * 32; i += 256) {
            int rr = i >> 5, kk = i & 31;
            int rg = (int)r0 + rr;
            ch[rr][kk] = (rg < N_NODES) ? x[(long long)rg * IN_C + cki * 32 + kk] : 0.f;
        }
        __syncthreads();
#pragma unroll 8
        for (int kk = 0; kk < 32; ++kk) {
            float xk = ch[t][kk];
            int kg = cki * 32 + kk;
#pragma unroll
            for (int o = 0; o < 16; ++o) p[o] += xk * Weff[kg * 16 + o];
        }
        __syncthreads();
    }
    for (int sck = 0; sck < 2; ++sck) {
        for (int i = t; i < 256 * 32; i += 256) {
            int rr = i >> 5, kk = i & 31;
            int rg = (int)r0 + rr;
            ch[rr][kk] = (rg < N_NODES) ? S[(long long)rg * 64 + sck * 32 + kk] : 0.f;
        }
        __syncthreads();
#pragma unroll 8
        for (int kk = 0; kk < 32; ++kk) {
            float xk = ch[t][kk];
            int kg = 128 + sck * 32 + kk;
#pragma unroll
            for (int o = 0; o < 16; ++o) p[o] += xk * Weff[kg * 16 + o];
        }
        __syncthreads();
    }

    if (r < N_NODES) {
        float m = p[0];
#pragma unroll
        for (int o = 1; o < 16; ++o) m = fmaxf(m, p[o]);
        float s = 0.f;
#pragma unroll
        for (int o = 0; o < 16; ++o) s += __expf(p[o] - m);
        float lse = m + logf(s);
        float4* o4 = (float4*)(out + (long long)r * 16);
#pragma unroll
        for (int q = 0; q < 4; ++q)
            o4[q] = make_float4(p[q * 4 + 0] - lse, p[q * 4 + 1] - lse,
                                p[q * 4 + 2] - lse, p[q * 4 + 3] - lse);
    }
}

extern "C" void kernel_launch(void* const* d_in, const int* in_sizes, int n_in,
                              void* d_out, int out_size, void* d_ws, size_t ws_size,
                              hipStream_t stream) {
    const float* x     = (const float*)d_in[0];
    const int*   ei    = (const int*)d_in[1];
    const float* MLPW  = (const float*)d_in[2];
    const float* MLPb  = (const float*)d_in[3];
    const float* mlpxW = (const float*)d_in[4];
    const float* mlpxb = (const float*)d_in[5];
    const float* finW  = (const float*)d_in[6];
    const float* finb  = (const float*)d_in[7];
    float* out = (float*)d_out;
    float* ws  = (float*)d_ws;

    float* WT      = ws;                                    // N*64 f
    float* S       = WT + (size_t)N_NODES * 64;             // N*64 f
    float* ssp     = S + (size_t)N_NODES * 64;              // 256*4096 f
    float* SS      = ssp + (size_t)SS_BLOCKS * 4096;        // 4096 f
    float* Weff    = SS + 4096;                             // 3072 f
    float* beff    = Weff + 192 * 16;                       // 16 f
    float* cutp    = beff + 16;                             // CUT_BLOCKS f
    float* dtp     = cutp + CUT_BLOCKS;                     // GATHER_BLOCKS f
    int*   counts  = (int*)(dtp + GATHER_BLOCKS);           // N i
    int*   offsets = counts + N_NODES;                      // N+1 i
    int*   cursor  = offsets + N_NODES + 1;                 // N i
    int*   csr_row = cursor + N_NODES;                      // E i
    int*   bsum    = csr_row + N_EDGES;                     // NSCAN_BLOCKS i
    int*   boff    = bsum + NSCAN_BLOCKS;                   // NSCAN_BLOCKS i

    hipLaunchKernelGGL(prep_weff, dim3(13), dim3(256), 0, stream,
                       mlpxW, mlpxb, finW, finb, Weff, beff);
    hipLaunchKernelGGL(transpose_w, dim3(TRANS_BLOCKS), dim3(256), 0, stream, MLPW, WT);
    hipLaunchKernelGGL(zero_counts, dim3((N_NODES + 255) / 256), dim3(256), 0, stream, counts);
    hipLaunchKernelGGL(hist_kernel, dim3(HIST_BLOCKS), dim3(256), 0, stream, ei, counts);
    hipLaunchKernelGGL(scan_reduce, dim3(NSCAN_BLOCKS), dim3(256), 0, stream, counts, bsum);
    hipLaunchKernelGGL(scan_toplevel, dim3(1), dim3(512), 0, stream, bsum, boff);
    hipLaunchKernelGGL(scan_apply, dim3(NSCAN_BLOCKS), dim3(256), 0, stream,
                       counts, boff, offsets, cursor);
    hipLaunchKernelGGL(fill_csr, dim3(FILL_BLOCKS), dim3(256), 0, stream, ei, cursor, csr_row);
    hipLaunchKernelGGL(gather_softmax, dim3(GATHER_BLOCKS), dim3(256), 0, stream,
                       offsets, csr_row, WT, MLPb, S, dtp);
    hipLaunchKernelGGL(cut_csr, dim3(CUT_BLOCKS), dim3(256), 0, stream,
                       offsets, csr_row, S, cutp);
    hipLaunchKernelGGL(ss_kernel, dim3(SS_BLOCKS), dim3(256), 0, stream, S, ssp);
    hipLaunchKernelGGL(reduce_ss, dim3(16), dim3(256), 0, stream, ssp, SS);
    hipLaunchKernelGGL(scalars_kernel, dim3(1), dim3(256), 0, stream, cutp, dtp, SS, out);
    hipLaunchKernelGGL(out_kernel, dim3(OUT_BLOCKS), dim3(256), 0, stream, x, S, Weff, beff, out);
}

// Round 4
// 470.531 us; speedup vs baseline: 2.0630x; 1.2985x over previous
//
#include <hip/hip_runtime.h>
#include <math.h>

#define N_NODES 100000
#define N_EDGES 1600000
#define IN_C    128
#define HID     256
#define KEIG    64
#define OUT_C   16

#define NPB      256                                   // nodes per bucket
#define NBUCKET  ((N_NODES + NPB - 1) / NPB)           // 391
#define EDGE_TILE 4096
#define NTILE    ((N_EDGES + EDGE_TILE - 1) / EDGE_TILE) // 391

#define TRANS_BLOCKS   ((N_NODES + 63) / 64)
#define GATHER_BLOCKS  2048
#define CUT_BLOCKS     2048
#define SS_BLOCKS      256
#define OUT_BLOCKS     ((N_NODES + 255) / 256)

__device__ __forceinline__ float wave_sum(float v) {
#pragma unroll
    for (int m = 32; m; m >>= 1) v += __shfl_xor(v, m, 64);
    return v;
}
__device__ __forceinline__ float wave_max(float v) {
#pragma unroll
    for (int m = 32; m; m >>= 1) v = fmaxf(v, __shfl_xor(v, m, 64));
    return v;
}
__device__ __forceinline__ float bf2f(unsigned short u) {
    return __uint_as_float(((unsigned int)u) << 16);
}
__device__ __forceinline__ unsigned short f2bf(float f) {
    unsigned int u = __float_as_uint(f);
    u += 0x7fff + ((u >> 16) & 1);
    return (unsigned short)(u >> 16);
}

// ---------------- small precompute (+ zero bucket counts) ----------------
__global__ void prep_weff(const float* __restrict__ mlpxW, const float* __restrict__ mlpxb,
                          const float* __restrict__ finW, const float* __restrict__ finb,
                          float* __restrict__ Weff, float* __restrict__ beff,
                          int* __restrict__ bcnt) {
    int t = blockIdx.x * blockDim.x + threadIdx.x;
    const int NW = (IN_C + KEIG) * OUT_C;
    if (t < NW) {
        int k = t >> 4, o = t & 15;
        float acc;
        if (k < IN_C) {
            acc = 0.f;
            for (int c = 0; c < HID; ++c)
                acc += mlpxW[c * IN_C + k] * finW[o * (HID + KEIG) + c];
        } else {
            acc = finW[o * (HID + KEIG) + HID + (k - IN_C)];
        }
        Weff[k * OUT_C + o] = acc;
    }
    int tb = t - NW;
    if (tb >= 0 && tb < OUT_C) {
        float acc = finb[tb];
        for (int c = 0; c < HID; ++c) acc += mlpxb[c] * finW[tb * (HID + KEIG) + c];
        beff[tb] = acc;
    }
    int tz = t - (NW + OUT_C);
    if (tz >= 0 && tz <= NBUCKET) bcnt[tz] = 0;
}

// MLP_W [64, N] -> WTb [N, 64] bf16
__global__ void transpose_w(const float* __restrict__ W, unsigned short* __restrict__ WTb) {
    __shared__ float tile[64][65];
    int n0 = blockIdx.x * 64;
    int t = threadIdx.x;
    int tn = t & 63, tq = t >> 6;
#pragma unroll
    for (int kk = 0; kk < 16; ++kk) {
        int k = tq * 16 + kk;
        int n = n0 + tn;
        tile[k][tn] = (n < N_NODES) ? W[(long long)k * N_NODES + n] : 0.f;
    }
    __syncthreads();
    int tk = t & 63;
#pragma unroll
    for (int ii = 0; ii < 16; ++ii) {
        int n = n0 + tq * 16 + ii;
        if (n < N_NODES) WTb[(long long)n * 64 + tk] = f2bf(tile[tk][tq * 16 + ii]);
    }
}

// ---------------- bucket sort CSR build ----------------
__global__ void bucket_hist(const int* __restrict__ ei, int* __restrict__ bcnt) {
    __shared__ int h[NBUCKET];
    int t = threadIdx.x;
    for (int i = t; i < NBUCKET; i += 256) h[i] = 0;
    __syncthreads();
    int e0 = blockIdx.x * EDGE_TILE;
    int e1 = min(e0 + EDGE_TILE, N_EDGES);
    for (int e = e0 + t; e < e1; e += 256)
        atomicAdd(&h[ei[N_EDGES + e] >> 8], 1);
    __syncthreads();
    for (int i = t; i < NBUCKET; i += 256)
        if (h[i]) atomicAdd(&bcnt[i], h[i]);
}

__global__ void bucket_scan(const int* __restrict__ bcnt, int* __restrict__ bbase,
                            int* __restrict__ bcur) {
    __shared__ int sh[512];
    int t = threadIdx.x;
    int v = (t < NBUCKET) ? bcnt[t] : 0;
    sh[t] = v;
    __syncthreads();
    for (int d = 1; d < 512; d <<= 1) {
        int u = (t >= d) ? sh[t - d] : 0;
        __syncthreads();
        sh[t] += u;
        __syncthreads();
    }
    if (t < NBUCKET) { bbase[t] = sh[t] - v; bcur[t] = sh[t] - v; }
    if (t == 0) bbase[NBUCKET] = N_EDGES;
}

// partition edges into bucket regions; pack r | (local_col << 17)
__global__ void bucket_scatter(const int* __restrict__ ei, int* __restrict__ bcur,
                               int* __restrict__ ebuf) {
    __shared__ int h[NBUCKET];
    __shared__ int gb[NBUCKET];
    int t = threadIdx.x;
    for (int i = t; i < NBUCKET; i += 256) h[i] = 0;
    __syncthreads();
    int e0 = blockIdx.x * EDGE_TILE;
    int e1 = min(e0 + EDGE_TILE, N_EDGES);
    for (int e = e0 + t; e < e1; e += 256)
        atomicAdd(&h[ei[N_EDGES + e] >> 8], 1);
    __syncthreads();
    for (int i = t; i < NBUCKET; i += 256) {
        int c = h[i];
        gb[i] = c ? atomicAdd(&bcur[i], c) : 0;
        h[i] = 0;                                // reuse as local cursor
    }
    __syncthreads();
    for (int e = e0 + t; e < e1; e += 256) {
        int r = ei[e];
        int c = ei[N_EDGES + e];
        int b = c >> 8;
        int pos = gb[b] + atomicAdd(&h[b], 1);
        ebuf[pos] = r | ((c & 255) << 17);
    }
}

// one block per bucket: LDS hist + scan -> offsets; LDS cursors -> csr_row
__global__ void csr_build(const int* __restrict__ ebuf, const int* __restrict__ bbase,
                          int* __restrict__ offsets, int* __restrict__ csr_row) {
    __shared__ int hist[NPB];
    __shared__ int sh[NPB];
    __shared__ int curs[NPB];
    int b = blockIdx.x;
    int t = threadIdx.x;
    int s0 = bbase[b], s1 = bbase[b + 1];
    hist[t] = 0;
    __syncthreads();
    for (int i = s0 + t; i < s1; i += 256)
        atomicAdd(&hist[ebuf[i] >> 17], 1);
    __syncthreads();
    int v = hist[t];
    sh[t] = v;
    __syncthreads();
    for (int d = 1; d < 256; d <<= 1) {
        int u = (t >= d) ? sh[t - d] : 0;
        __syncthreads();
        sh[t] += u;
        __syncthreads();
    }
    int excl = s0 + sh[t] - v;
    int node = b * NPB + t;
    if (node < N_NODES) offsets[node] = excl;
    curs[t] = excl;
    __syncthreads();
    for (int i = s0 + t; i < s1; i += 256) {
        int pk = ebuf[i];
        int pos = atomicAdd(&curs[pk >> 17], 1);
        csr_row[pos] = pk & 0x1FFFF;
    }
    if (b == 0 && t == 0) offsets[N_NODES] = N_EDGES;
}

// ---------------- pass 1: gather + bias + softmax + deg_term ----------------
__global__ void gather_softmax(const int* __restrict__ offsets, const int* __restrict__ csr_row,
                               const unsigned short* __restrict__ WTb,
                               const float* __restrict__ MLPb,
                               float* __restrict__ S, unsigned short* __restrict__ Sb,
                               float* __restrict__ dtp) {
    int lane = threadIdx.x & 63;
    int wib = threadIdx.x >> 6;
    int gw = (blockIdx.x * blockDim.x + threadIdx.x) >> 6;
    int nw = (gridDim.x * blockDim.x) >> 6;
    float bias = MLPb[lane];
    float dacc = 0.f;
    for (int n = gw; n < N_NODES; n += nw) {
        int s0 = offsets[n], s1 = offsets[n + 1];
        float acc = bias;
        for (int base = s0; base < s1; base += 64) {
            int cnt = min(64, s1 - base);
            int rv = (lane < cnt) ? csr_row[base + lane] : 0;
            int j = 0;
            for (; j + 3 < cnt; j += 4) {
                int r0 = __shfl(rv, j, 64);
                int r1 = __shfl(rv, j + 1, 64);
                int r2 = __shfl(rv, j + 2, 64);
                int r3 = __shfl(rv, j + 3, 64);
                float v0 = bf2f(WTb[(long long)r0 * 64 + lane]);
                float v1 = bf2f(WTb[(long long)r1 * 64 + lane]);
                float v2 = bf2f(WTb[(long long)r2 * 64 + lane]);
                float v3 = bf2f(WTb[(long long)r3 * 64 + lane]);
                acc += (v0 + v1) + (v2 + v3);
            }
            for (; j < cnt; ++j) {
                int r = __shfl(rv, j, 64);
                acc += bf2f(WTb[(long long)r * 64 + lane]);
            }
        }
        float m = wave_max(acc);
        float e = __expf(acc - m);
        float sm = wave_sum(e);
        float sv = e / sm;
        S[(long long)n * 64 + lane] = sv;
        Sb[(long long)n * 64 + lane] = f2bf(sv);
        dacc += (float)(s1 - s0) * sv * sv;
    }
    dacc = wave_sum(dacc);
    __shared__ float red[4];
    if (lane == 0) red[wib] = dacc;
    __syncthreads();
    if (threadIdx.x == 0) dtp[blockIdx.x] = red[0] + red[1] + red[2] + red[3];
}

// ---------------- pass 2: cut ----------------
__global__ void cut_csr(const int* __restrict__ offsets, const int* __restrict__ csr_row,
                        const unsigned short* __restrict__ Sb, float* __restrict__ cutp) {
    int lane = threadIdx.x & 63;
    int wib = threadIdx.x >> 6;
    int gw = (blockIdx.x * blockDim.x + threadIdx.x) >> 6;
    int nw = (gridDim.x * blockDim.x) >> 6;
    float acc = 0.f;
    for (int n = gw; n < N_NODES; n += nw) {
        float sc = bf2f(Sb[(long long)n * 64 + lane]);
        int s0 = offsets[n], s1 = offsets[n + 1];
        float g = 0.f;
        for (int base = s0; base < s1; base += 64) {
            int cnt = min(64, s1 - base);
            int rv = (lane < cnt) ? csr_row[base + lane] : 0;
            int j = 0;
            for (; j + 3 < cnt; j += 4) {
                int r0 = __shfl(rv, j, 64);
                int r1 = __shfl(rv, j + 1, 64);
                int r2 = __shfl(rv, j + 2, 64);
                int r3 = __shfl(rv, j + 3, 64);
                float v0 = bf2f(Sb[(long long)r0 * 64 + lane]);
                float v1 = bf2f(Sb[(long long)r1 * 64 + lane]);
                float v2 = bf2f(Sb[(long long)r2 * 64 + lane]);
                float v3 = bf2f(Sb[(long long)r3 * 64 + lane]);
                g += (v0 + v1) + (v2 + v3);
            }
            for (; j < cnt; ++j) {
                int r = __shfl(rv, j, 64);
                g += bf2f(Sb[(long long)r * 64 + lane]);
            }
        }
        acc += sc * g;
    }
    acc = wave_sum(acc);
    __shared__ float red[4];
    if (lane == 0) red[wib] = acc;
    __syncthreads();
    if (threadIdx.x == 0) cutp[blockIdx.x] = red[0] + red[1] + red[2] + red[3];
}

// ---------------- SS = S^T S, per-block partials ----------------
__global__ void ss_kernel(const float* __restrict__ S, float* __restrict__ ssp) {
    __shared__ float Sr[32][65];
    int t = threadIdx.x;
    int a = t & 63, bq = t >> 6;
    float acc[16];
#pragma unroll
    for (int j = 0; j < 16; ++j) acc[j] = 0.f;
    for (int base = blockIdx.x * 32; base < N_NODES; base += gridDim.x * 32) {
        int nr = min(32, N_NODES - base);
        for (int i = t; i < 32 * 64; i += 256) {
            int rr = i >> 6, cc = i & 63;
            Sr[rr][cc] = (rr < nr) ? S[(long long)(base + rr) * 64 + cc] : 0.f;
        }
        __syncthreads();
        for (int rr = 0; rr < 32; ++rr) {
            float va = Sr[rr][a];
#pragma unroll
            for (int j = 0; j < 16; ++j) acc[j] += va * Sr[rr][bq * 16 + j];
        }
        __syncthreads();
    }
    float* dst = ssp + (size_t)blockIdx.x * 4096;
#pragma unroll
    for (int j = 0; j < 16; ++j) dst[a * 64 + bq * 16 + j] = acc[j];
}

__global__ void reduce_ss(const float* __restrict__ ssp, float* __restrict__ SS) {
    int e = blockIdx.x * blockDim.x + threadIdx.x;
    float s = 0.f;
    for (int p = 0; p < SS_BLOCKS; ++p) s += ssp[(size_t)p * 4096 + e];
    SS[e] = s;
}

// ---------------- scalar losses ----------------
__global__ void scalars_kernel(const float* __restrict__ cutp, const float* __restrict__ dtp,
                               const float* __restrict__ SS, float* __restrict__ out) {
    __shared__ float red[256];
    int t = threadIdx.x;
    float c = 0.f;
    for (int i = t; i < CUT_BLOCKS; i += 256) c += cutp[i];
    red[t] = c; __syncthreads();
    for (int s = 128; s; s >>= 1) { if (t < s) red[t] += red[t + s]; __syncthreads(); }
    float cut = red[0]; __syncthreads();

    float d = 0.f;
    for (int i = t; i < GATHER_BLOCKS; i += 256) d += dtp[i];
    red[t] = d; __syncthreads();
    for (int s = 128; s; s >>= 1) { if (t < s) red[t] += red[t + s]; __syncthreads(); }
    float dterm = red[0]; __syncthreads();

    float ss[16];
    float sq = 0.f;
#pragma unroll
    for (int j = 0; j < 16; ++j) { ss[j] = SS[t * 16 + j]; sq += ss[j] * ss[j]; }
    red[t] = sq; __syncthreads();
    for (int s = 128; s; s >>= 1) { if (t < s) red[t] += red[t + s]; __syncthreads(); }
    float nrm = sqrtf(red[0]); __syncthreads();

    float osq = 0.f;
#pragma unroll
    for (int j = 0; j < 16; ++j) {
        int idx = t * 16 + j;
        float v = ss[j] / nrm - ((idx % 65 == 0) ? 0.125f : 0.f);
        osq += v * v;
    }
    red[t] = osq; __syncthreads();
    for (int s = 128; s; s >>= 1) { if (t < s) red[t] += red[t + s]; __syncthreads(); }
    if (t == 0) {
        float loss = -(cut / dterm) + sqrtf(red[0]);
        out[(long long)N_NODES * OUT_C] = loss;
    }
}

// ---------------- output: logits + log_softmax ----------------
__global__ void out_kernel(const float* __restrict__ x, const float* __restrict__ S,
                           const float* __restrict__ Weff, const float* __restrict__ beff,
                           float* __restrict__ out) {
    __shared__ float ch[256][33];
    int t = threadIdx.x;
    long long r0 = (long long)blockIdx.x * 256;
    int r = (int)r0 + t;
    float p[16];
#pragma unroll
    for (int o = 0; o < 16; ++o) p[o] = beff[o];

    for (int cki = 0; cki < 4; ++cki) {
        for (int i = t; i < 256 * 32; i += 256) {
            int rr = i >> 5, kk = i & 31;
            int rg = (int)r0 + rr;
            ch[rr][kk] = (rg < N_NODES) ? x[(long long)rg * IN_C + cki * 32 + kk] : 0.f;
        }
        __syncthreads();
#pragma unroll 8
        for (int kk = 0; kk < 32; ++kk) {
            float xk = ch[t][kk];
            int kg = cki * 32 + kk;
#pragma unroll
            for (int o = 0; o < 16; ++o) p[o] += xk * Weff[kg * 16 + o];
        }
        __syncthreads();
    }
    for (int sck = 0; sck < 2; ++sck) {
        for (int i = t; i < 256 * 32; i += 256) {
            int rr = i >> 5, kk = i & 31;
            int rg = (int)r0 + rr;
            ch[rr][kk] = (rg < N_NODES) ? S[(long long)rg * 64 + sck * 32 + kk] : 0.f;
        }
        __syncthreads();
#pragma unroll 8
        for (int kk = 0; kk < 32; ++kk) {
            float xk = ch[t][kk];
            int kg = 128 + sck * 32 + kk;
#pragma unroll
            for (int o = 0; o < 16; ++o) p[o] += xk * Weff[kg * 16 + o];
        }
        __syncthreads();
    }

    if (r < N_NODES) {
        float m = p[0];
#pragma unroll
        for (int o = 1; o < 16; ++o) m = fmaxf(m, p[o]);
        float s = 0.f;
#pragma unroll
        for (int o = 0; o < 16; ++o) s += __expf(p[o] - m);
        float lse = m + logf(s);
        float4* o4 = (float4*)(out + (long long)r * 16);
#pragma unroll
        for (int q = 0; q < 4; ++q)
            o4[q] = make_float4(p[q * 4 + 0] - lse, p[q * 4 + 1] - lse,
                                p[q * 4 + 2] - lse, p[q * 4 + 3] - lse);
    }
}

extern "C" void kernel_launch(void* const* d_in, const int* in_sizes, int n_in,
                              void* d_out, int out_size, void* d_ws, size_t ws_size,
                              hipStream_t stream) {
    const float* x     = (const float*)d_in[0];
    const int*   ei    = (const int*)d_in[1];
    const float* MLPW  = (const float*)d_in[2];
    const float* MLPb  = (const float*)d_in[3];
    const float* mlpxW = (const float*)d_in[4];
    const float* mlpxb = (const float*)d_in[5];
    const float* finW  = (const float*)d_in[6];
    const float* finb  = (const float*)d_in[7];
    float* out = (float*)d_out;
    float* ws  = (float*)d_ws;

    unsigned short* WTb = (unsigned short*)ws;                       // N*64 bf16
    float* S    = ws + (size_t)N_NODES * 32;                         // N*64 f32
    unsigned short* Sb = (unsigned short*)(S + (size_t)N_NODES * 64);// N*64 bf16
    float* ssp  = S + (size_t)N_NODES * 64 + (size_t)N_NODES * 32;   // 256*4096
    float* SS   = ssp + (size_t)SS_BLOCKS * 4096;                    // 4096
    float* Weff = SS + 4096;                                         // 3072
    float* beff = Weff + 192 * 16;                                   // 16
    float* cutp = beff + 16;                                         // CUT_BLOCKS
    float* dtp  = cutp + CUT_BLOCKS;                                 // GATHER_BLOCKS
    int* ebuf    = (int*)(dtp + GATHER_BLOCKS);                      // E
    int* csr_row = ebuf + N_EDGES;                                   // E
    int* offsets = csr_row + N_EDGES;                                // N+1
    int* bcnt    = offsets + N_NODES + 1;                            // NBUCKET+1
    int* bbase   = bcnt + NBUCKET + 1;                               // NBUCKET+1
    int* bcur    = bbase + NBUCKET + 1;                              // NBUCKET

    hipLaunchKernelGGL(prep_weff, dim3(14), dim3(256), 0, stream,
                       mlpxW, mlpxb, finW, finb, Weff, beff, bcnt);
    hipLaunchKernelGGL(transpose_w, dim3(TRANS_BLOCKS), dim3(256), 0, stream, MLPW, WTb);
    hipLaunchKernelGGL(bucket_hist, dim3(NTILE), dim3(256), 0, stream, ei, bcnt);
    hipLaunchKernelGGL(bucket_scan, dim3(1), dim3(512), 0, stream, bcnt, bbase, bcur);
    hipLaunchKernelGGL(bucket_scatter, dim3(NTILE), dim3(256), 0, stream, ei, bcur, ebuf);
    hipLaunchKernelGGL(csr_build, dim3(NBUCKET), dim3(256), 0, stream,
                       ebuf, bbase, offsets, csr_row);
    hipLaunchKernelGGL(gather_softmax, dim3(GATHER_BLOCKS), dim3(256), 0, stream,
                       offsets, csr_row, WTb, MLPb, S, Sb, dtp);
    hipLaunchKernelGGL(cut_csr, dim3(CUT_BLOCKS), dim3(256), 0, stream,
                       offsets, csr_row, Sb, cutp);
    hipLaunchKernelGGL(ss_kernel, dim3(SS_BLOCKS), dim3(256), 0, stream, S, ssp);
    hipLaunchKernelGGL(reduce_ss, dim3(16), dim3(256), 0, stream, ssp, SS);
    hipLaunchKernelGGL(scalars_kernel, dim3(1), dim3(256), 0, stream, cutp, dtp, SS, out);
    hipLaunchKernelGGL(out_kernel, dim3(OUT_BLOCKS), dim3(256), 0, stream, x, S, Weff, beff, out);
}

// Round 5
// 404.878 us; speedup vs baseline: 2.3975x; 1.1622x over previous
//
#include <hip/hip_runtime.h>
#include <math.h>

#define N_NODES 100000
#define N_EDGES 1600000
#define IN_C    128
#define HID     256
#define KEIG    64
#define OUT_C   16

#define NPB      256                                   // nodes per bucket
#define NBUCKET  ((N_NODES + NPB - 1) / NPB)           // 391
#define EDGE_TILE 4096
#define NTILE    ((N_EDGES + EDGE_TILE - 1) / EDGE_TILE) // 391

#define TRANS_BLOCKS   ((N_NODES + 63) / 64)
#define GATHER_BLOCKS  2048
#define CUT_BLOCKS     2048
#define SS_BLOCKS      256
#define OUT_BLOCKS     ((N_NODES + 255) / 256)

__device__ __forceinline__ float wave_sum(float v) {
#pragma unroll
    for (int m = 32; m; m >>= 1) v += __shfl_xor(v, m, 64);
    return v;
}
__device__ __forceinline__ float wave_max(float v) {
#pragma unroll
    for (int m = 32; m; m >>= 1) v = fmaxf(v, __shfl_xor(v, m, 64));
    return v;
}
__device__ __forceinline__ float bf2f(unsigned int u) {
    return __uint_as_float((u & 0xffffu) << 16);
}
__device__ __forceinline__ unsigned short f2bf(float f) {
    unsigned int u = __float_as_uint(f);
    u += 0x7fff + ((u >> 16) & 1);
    return (unsigned short)(u >> 16);
}

#define FMA4(P, s, W) \
    P.x = fmaf(s, W.x, P.x); P.y = fmaf(s, W.y, P.y); \
    P.z = fmaf(s, W.z, P.z); P.w = fmaf(s, W.w, P.w);

// ---------------- small precompute (+ zero bucket counts) ----------------
__global__ void prep_weff(const float* __restrict__ mlpxW, const float* __restrict__ mlpxb,
                          const float* __restrict__ finW, const float* __restrict__ finb,
                          float* __restrict__ Weff, float* __restrict__ beff,
                          int* __restrict__ bcnt) {
    int t = blockIdx.x * blockDim.x + threadIdx.x;
    const int NW = (IN_C + KEIG) * OUT_C;
    if (t < NW) {
        int k = t >> 4, o = t & 15;
        float acc;
        if (k < IN_C) {
            acc = 0.f;
            for (int c = 0; c < HID; ++c)
                acc += mlpxW[c * IN_C + k] * finW[o * (HID + KEIG) + c];
        } else {
            acc = finW[o * (HID + KEIG) + HID + (k - IN_C)];
        }
        Weff[k * OUT_C + o] = acc;
    }
    int tb = t - NW;
    if (tb >= 0 && tb < OUT_C) {
        float acc = finb[tb];
        for (int c = 0; c < HID; ++c) acc += mlpxb[c] * finW[tb * (HID + KEIG) + c];
        beff[tb] = acc;
    }
    int tz = t - (NW + OUT_C);
    if (tz >= 0 && tz <= NBUCKET) bcnt[tz] = 0;
}

// MLP_W [64, N] -> WTb [N, 64] bf16
__global__ void transpose_w(const float* __restrict__ W, unsigned short* __restrict__ WTb) {
    __shared__ float tile[64][65];
    int n0 = blockIdx.x * 64;
    int t = threadIdx.x;
    int tn = t & 63, tq = t >> 6;
#pragma unroll
    for (int kk = 0; kk < 16; ++kk) {
        int k = tq * 16 + kk;
        int n = n0 + tn;
        tile[k][tn] = (n < N_NODES) ? W[(long long)k * N_NODES + n] : 0.f;
    }
    __syncthreads();
    int tk = t & 63;
#pragma unroll
    for (int ii = 0; ii < 16; ++ii) {
        int n = n0 + tq * 16 + ii;
        if (n < N_NODES) WTb[(long long)n * 64 + tk] = f2bf(tile[tk][tq * 16 + ii]);
    }
}

// ---------------- bucket sort CSR build ----------------
__global__ void bucket_hist(const int* __restrict__ ei, int* __restrict__ bcnt) {
    __shared__ int h[NBUCKET];
    int t = threadIdx.x;
    for (int i = t; i < NBUCKET; i += 256) h[i] = 0;
    __syncthreads();
    int e0 = blockIdx.x * EDGE_TILE;
    int e1 = min(e0 + EDGE_TILE, N_EDGES);
    for (int e = e0 + t; e < e1; e += 256)
        atomicAdd(&h[ei[N_EDGES + e] >> 8], 1);
    __syncthreads();
    for (int i = t; i < NBUCKET; i += 256)
        if (h[i]) atomicAdd(&bcnt[i], h[i]);
}

__global__ void bucket_scan(const int* __restrict__ bcnt, int* __restrict__ bbase,
                            int* __restrict__ bcur) {
    __shared__ int sh[512];
    int t = threadIdx.x;
    int v = (t < NBUCKET) ? bcnt[t] : 0;
    sh[t] = v;
    __syncthreads();
    for (int d = 1; d < 512; d <<= 1) {
        int u = (t >= d) ? sh[t - d] : 0;
        __syncthreads();
        sh[t] += u;
        __syncthreads();
    }
    if (t < NBUCKET) { bbase[t] = sh[t] - v; bcur[t] = sh[t] - v; }
    if (t == 0) bbase[NBUCKET] = N_EDGES;
}

// partition edges into bucket regions; pack r | (local_col << 17)
__global__ void bucket_scatter(const int* __restrict__ ei, int* __restrict__ bcur,
                               int* __restrict__ ebuf) {
    __shared__ int h[NBUCKET];
    __shared__ int gb[NBUCKET];
    int t = threadIdx.x;
    for (int i = t; i < NBUCKET; i += 256) h[i] = 0;
    __syncthreads();
    int e0 = blockIdx.x * EDGE_TILE;
    int e1 = min(e0 + EDGE_TILE, N_EDGES);
    for (int e = e0 + t; e < e1; e += 256)
        atomicAdd(&h[ei[N_EDGES + e] >> 8], 1);
    __syncthreads();
    for (int i = t; i < NBUCKET; i += 256) {
        int c = h[i];
        gb[i] = c ? atomicAdd(&bcur[i], c) : 0;
        h[i] = 0;                                // reuse as local cursor
    }
    __syncthreads();
    for (int e = e0 + t; e < e1; e += 256) {
        int r = ei[e];
        int c = ei[N_EDGES + e];
        int b = c >> 8;
        int pos = gb[b] + atomicAdd(&h[b], 1);
        ebuf[pos] = r | ((c & 255) << 17);
    }
}

// one block per bucket: LDS hist + scan -> offsets; LDS cursors -> csr_row
__global__ void csr_build(const int* __restrict__ ebuf, const int* __restrict__ bbase,
                          int* __restrict__ offsets, int* __restrict__ csr_row) {
    __shared__ int hist[NPB];
    __shared__ int sh[NPB];
    __shared__ int curs[NPB];
    int b = blockIdx.x;
    int t = threadIdx.x;
    int s0 = bbase[b], s1 = bbase[b + 1];
    hist[t] = 0;
    __syncthreads();
    for (int i = s0 + t; i < s1; i += 256)
        atomicAdd(&hist[ebuf[i] >> 17], 1);
    __syncthreads();
    int v = hist[t];
    sh[t] = v;
    __syncthreads();
    for (int d = 1; d < 256; d <<= 1) {
        int u = (t >= d) ? sh[t - d] : 0;
        __syncthreads();
        sh[t] += u;
        __syncthreads();
    }
    int excl = s0 + sh[t] - v;
    int node = b * NPB + t;
    if (node < N_NODES) offsets[node] = excl;
    curs[t] = excl;
    __syncthreads();
    for (int i = s0 + t; i < s1; i += 256) {
        int pk = ebuf[i];
        int pos = atomicAdd(&curs[pk >> 17], 1);
        csr_row[pos] = pk & 0x1FFFF;
    }
    if (b == 0 && t == 0) offsets[N_NODES] = N_EDGES;
}

// ---------------- pass 1: gather + bias + softmax + deg_term ----------------
__global__ void gather_softmax(const int* __restrict__ offsets, const int* __restrict__ csr_row,
                               const unsigned short* __restrict__ WTb,
                               const float* __restrict__ MLPb,
                               unsigned short* __restrict__ Sb,
                               float* __restrict__ dtp) {
    int lane = threadIdx.x & 63;
    int wib = threadIdx.x >> 6;
    int gw = (blockIdx.x * blockDim.x + threadIdx.x) >> 6;
    int nw = (gridDim.x * blockDim.x) >> 6;
    float bias = MLPb[lane];
    float dacc = 0.f;
    for (int n = gw; n < N_NODES; n += nw) {
        int s0 = offsets[n], s1 = offsets[n + 1];
        float acc = bias;
        for (int base = s0; base < s1; base += 64) {
            int cnt = min(64, s1 - base);
            int rv = (lane < cnt) ? csr_row[base + lane] : 0;
            int j = 0;
            for (; j + 3 < cnt; j += 4) {
                int r0 = __shfl(rv, j, 64);
                int r1 = __shfl(rv, j + 1, 64);
                int r2 = __shfl(rv, j + 2, 64);
                int r3 = __shfl(rv, j + 3, 64);
                float v0 = bf2f(WTb[(long long)r0 * 64 + lane]);
                float v1 = bf2f(WTb[(long long)r1 * 64 + lane]);
                float v2 = bf2f(WTb[(long long)r2 * 64 + lane]);
                float v3 = bf2f(WTb[(long long)r3 * 64 + lane]);
                acc += (v0 + v1) + (v2 + v3);
            }
            for (; j < cnt; ++j) {
                int r = __shfl(rv, j, 64);
                acc += bf2f(WTb[(long long)r * 64 + lane]);
            }
        }
        float m = wave_max(acc);
        float e = __expf(acc - m);
        float sm = wave_sum(e);
        float sv = e / sm;
        Sb[(long long)n * 64 + lane] = f2bf(sv);
        dacc += (float)(s1 - s0) * sv * sv;
    }
    dacc = wave_sum(dacc);
    __shared__ float red[4];
    if (lane == 0) red[wib] = dacc;
    __syncthreads();
    if (threadIdx.x == 0) dtp[blockIdx.x] = red[0] + red[1] + red[2] + red[3];
}

// ---------------- pass 2: cut ----------------
__global__ void cut_csr(const int* __restrict__ offsets, const int* __restrict__ csr_row,
                        const unsigned short* __restrict__ Sb, float* __restrict__ cutp) {
    int lane = threadIdx.x & 63;
    int wib = threadIdx.x >> 6;
    int gw = (blockIdx.x * blockDim.x + threadIdx.x) >> 6;
    int nw = (gridDim.x * blockDim.x) >> 6;
    float acc = 0.f;
    for (int n = gw; n < N_NODES; n += nw) {
        float sc = bf2f(Sb[(long long)n * 64 + lane]);
        int s0 = offsets[n], s1 = offsets[n + 1];
        float g = 0.f;
        for (int base = s0; base < s1; base += 64) {
            int cnt = min(64, s1 - base);
            int rv = (lane < cnt) ? csr_row[base + lane] : 0;
            int j = 0;
            for (; j + 3 < cnt; j += 4) {
                int r0 = __shfl(rv, j, 64);
                int r1 = __shfl(rv, j + 1, 64);
                int r2 = __shfl(rv, j + 2, 64);
                int r3 = __shfl(rv, j + 3, 64);
                float v0 = bf2f(Sb[(long long)r0 * 64 + lane]);
                float v1 = bf2f(Sb[(long long)r1 * 64 + lane]);
                float v2 = bf2f(Sb[(long long)r2 * 64 + lane]);
                float v3 = bf2f(Sb[(long long)r3 * 64 + lane]);
                g += (v0 + v1) + (v2 + v3);
            }
            for (; j < cnt; ++j) {
                int r = __shfl(rv, j, 64);
                g += bf2f(Sb[(long long)r * 64 + lane]);
            }
        }
        acc += sc * g;
    }
    acc = wave_sum(acc);
    __shared__ float red[4];
    if (lane == 0) red[wib] = acc;
    __syncthreads();
    if (threadIdx.x == 0) cutp[blockIdx.x] = red[0] + red[1] + red[2] + red[3];
}

// ---------------- SS = S^T S (from bf16 S), per-block partials ----------------
__global__ void ss_kernel(const unsigned short* __restrict__ Sb, float* __restrict__ ssp) {
    __shared__ float Sr[32][65];
    int t = threadIdx.x;
    int a = t & 63, bq = t >> 6;
    float acc[16];
#pragma unroll
    for (int j = 0; j < 16; ++j) acc[j] = 0.f;
    const unsigned int* S32 = (const unsigned int*)Sb;
    for (int base = blockIdx.x * 32; base < N_NODES; base += gridDim.x * 32) {
        int nr = min(32, N_NODES - base);
        for (int i = t; i < 32 * 32; i += 256) {
            int rr = i >> 5, cp = i & 31;
            unsigned int u = (rr < nr) ? S32[(long long)(base + rr) * 32 + cp] : 0u;
            Sr[rr][cp * 2]     = bf2f(u);
            Sr[rr][cp * 2 + 1] = bf2f(u >> 16);
        }
        __syncthreads();
        for (int rr = 0; rr < 32; ++rr) {
            float va = Sr[rr][a];
#pragma unroll
            for (int j = 0; j < 16; ++j) acc[j] += va * Sr[rr][bq * 16 + j];
        }
        __syncthreads();
    }
    float* dst = ssp + (size_t)blockIdx.x * 4096;
#pragma unroll
    for (int j = 0; j < 16; ++j) dst[a * 64 + bq * 16 + j] = acc[j];
}

__global__ void reduce_ss(const float* __restrict__ ssp, float* __restrict__ SS) {
    int e = blockIdx.x * blockDim.x + threadIdx.x;
    float s = 0.f;
    for (int p = 0; p < SS_BLOCKS; ++p) s += ssp[(size_t)p * 4096 + e];
    SS[e] = s;
}

// ---------------- scalar losses ----------------
__global__ void scalars_kernel(const float* __restrict__ cutp, const float* __restrict__ dtp,
                               const float* __restrict__ SS, float* __restrict__ out) {
    __shared__ float red[256];
    int t = threadIdx.x;
    float c = 0.f;
    for (int i = t; i < CUT_BLOCKS; i += 256) c += cutp[i];
    red[t] = c; __syncthreads();
    for (int s = 128; s; s >>= 1) { if (t < s) red[t] += red[t + s]; __syncthreads(); }
    float cut = red[0]; __syncthreads();

    float d = 0.f;
    for (int i = t; i < GATHER_BLOCKS; i += 256) d += dtp[i];
    red[t] = d; __syncthreads();
    for (int s = 128; s; s >>= 1) { if (t < s) red[t] += red[t + s]; __syncthreads(); }
    float dterm = red[0]; __syncthreads();

    float ss[16];
    float sq = 0.f;
#pragma unroll
    for (int j = 0; j < 16; ++j) { ss[j] = SS[t * 16 + j]; sq += ss[j] * ss[j]; }
    red[t] = sq; __syncthreads();
    for (int s = 128; s; s >>= 1) { if (t < s) red[t] += red[t + s]; __syncthreads(); }
    float nrm = sqrtf(red[0]); __syncthreads();

    float osq = 0.f;
#pragma unroll
    for (int j = 0; j < 16; ++j) {
        int idx = t * 16 + j;
        float v = ss[j] / nrm - ((idx % 65 == 0) ? 0.125f : 0.f);
        osq += v * v;
    }
    red[t] = osq; __syncthreads();
    for (int s = 128; s; s >>= 1) { if (t < s) red[t] += red[t + s]; __syncthreads(); }
    if (t == 0) {
        float loss = -(cut / dterm) + sqrtf(red[0]);
        out[(long long)N_NODES * OUT_C] = loss;
    }
}

// ---------------- output: barrier-free, one thread per row ----------------
__global__ __launch_bounds__(256) void out_kernel(const float* __restrict__ x,
                           const unsigned short* __restrict__ Sb,
                           const float* __restrict__ Weff, const float* __restrict__ beff,
                           float* __restrict__ out) {
    __shared__ float4 Wsh[192 * 4];   // Wsh[k*4+q] = Weff[k][4q..4q+3]
    __shared__ float bsh[16];
    int t = threadIdx.x;
    const float4* W4 = (const float4*)Weff;
    for (int i = t; i < 768; i += 256) Wsh[i] = W4[i];
    if (t < 16) bsh[t] = beff[t];
    __syncthreads();

    int r = blockIdx.x * 256 + t;
    if (r >= N_NODES) return;

    float4 p0 = make_float4(bsh[0], bsh[1], bsh[2], bsh[3]);
    float4 p1 = make_float4(bsh[4], bsh[5], bsh[6], bsh[7]);
    float4 p2 = make_float4(bsh[8], bsh[9], bsh[10], bsh[11]);
    float4 p3 = make_float4(bsh[12], bsh[13], bsh[14], bsh[15]);

    const float4* xr = (const float4*)(x + (long long)r * IN_C);
#pragma unroll 8
    for (int j = 0; j < 32; ++j) {
        float4 xv = xr[j];
        int k = j * 4;
        float xs[4] = {xv.x, xv.y, xv.z, xv.w};
#pragma unroll
        for (int c = 0; c < 4; ++c) {
            float s = xs[c];
            float4 w0 = Wsh[(k + c) * 4 + 0];
            float4 w1 = Wsh[(k + c) * 4 + 1];
            float4 w2 = Wsh[(k + c) * 4 + 2];
            float4 w3 = Wsh[(k + c) * 4 + 3];
            FMA4(p0, s, w0); FMA4(p1, s, w1); FMA4(p2, s, w2); FMA4(p3, s, w3);
        }
    }
    const uint2* sr = (const uint2*)(Sb + (long long)r * 64);
#pragma unroll 8
    for (int j = 0; j < 16; ++j) {
        uint2 u = sr[j];
        float xs[4] = {bf2f(u.x), bf2f(u.x >> 16), bf2f(u.y), bf2f(u.y >> 16)};
        int k = IN_C + j * 4;
#pragma unroll
        for (int c = 0; c < 4; ++c) {
            float s = xs[c];
            float4 w0 = Wsh[(k + c) * 4 + 0];
            float4 w1 = Wsh[(k + c) * 4 + 1];
            float4 w2 = Wsh[(k + c) * 4 + 2];
            float4 w3 = Wsh[(k + c) * 4 + 3];
            FMA4(p0, s, w0); FMA4(p1, s, w1); FMA4(p2, s, w2); FMA4(p3, s, w3);
        }
    }

    float m = fmaxf(fmaxf(fmaxf(p0.x, p0.y), fmaxf(p0.z, p0.w)),
                    fmaxf(fmaxf(fmaxf(p1.x, p1.y), fmaxf(p1.z, p1.w)),
                          fmaxf(fmaxf(fmaxf(p2.x, p2.y), fmaxf(p2.z, p2.w)),
                                fmaxf(fmaxf(p3.x, p3.y), fmaxf(p3.z, p3.w)))));
    float sum = __expf(p0.x - m) + __expf(p0.y - m) + __expf(p0.z - m) + __expf(p0.w - m)
              + __expf(p1.x - m) + __expf(p1.y - m) + __expf(p1.z - m) + __expf(p1.w - m)
              + __expf(p2.x - m) + __expf(p2.y - m) + __expf(p2.z - m) + __expf(p2.w - m)
              + __expf(p3.x - m) + __expf(p3.y - m) + __expf(p3.z - m) + __expf(p3.w - m);
    float lse = m + logf(sum);
    float4* o4 = (float4*)(out + (long long)r * OUT_C);
    o4[0] = make_float4(p0.x - lse, p0.y - lse, p0.z - lse, p0.w - lse);
    o4[1] = make_float4(p1.x - lse, p1.y - lse, p1.z - lse, p1.w - lse);
    o4[2] = make_float4(p2.x - lse, p2.y - lse, p2.z - lse, p2.w - lse);
    o4[3] = make_float4(p3.x - lse, p3.y - lse, p3.z - lse, p3.w - lse);
}

extern "C" void kernel_launch(void* const* d_in, const int* in_sizes, int n_in,
                              void* d_out, int out_size, void* d_ws, size_t ws_size,
                              hipStream_t stream) {
    const float* x     = (const float*)d_in[0];
    const int*   ei    = (const int*)d_in[1];
    const float* MLPW  = (const float*)d_in[2];
    const float* MLPb  = (const float*)d_in[3];
    const float* mlpxW = (const float*)d_in[4];
    const float* mlpxb = (const float*)d_in[5];
    const float* finW  = (const float*)d_in[6];
    const float* finb  = (const float*)d_in[7];
    float* out = (float*)d_out;
    float* ws  = (float*)d_ws;

    unsigned short* WTb = (unsigned short*)ws;                       // N*64 bf16
    unsigned short* Sb  = (unsigned short*)(ws + (size_t)N_NODES * 32); // N*64 bf16
    float* ssp  = ws + (size_t)N_NODES * 64;                         // 256*4096
    float* SS   = ssp + (size_t)SS_BLOCKS * 4096;                    // 4096
    float* Weff = SS + 4096;                                         // 3072
    float* beff = Weff + 192 * 16;                                   // 16
    float* cutp = beff + 16;                                         // CUT_BLOCKS
    float* dtp  = cutp + CUT_BLOCKS;                                 // GATHER_BLOCKS
    int* ebuf    = (int*)(dtp + GATHER_BLOCKS);                      // E
    int* csr_row = ebuf + N_EDGES;                                   // E
    int* offsets = csr_row + N_EDGES;                                // N+1
    int* bcnt    = offsets + N_NODES + 1;                            // NBUCKET+1
    int* bbase   = bcnt + NBUCKET + 1;                               // NBUCKET+1
    int* bcur    = bbase + NBUCKET + 1;                              // NBUCKET

    hipLaunchKernelGGL(prep_weff, dim3(14), dim3(256), 0, stream,
                       mlpxW, mlpxb, finW, finb, Weff, beff, bcnt);
    hipLaunchKernelGGL(transpose_w, dim3(TRANS_BLOCKS), dim3(256), 0, stream, MLPW, WTb);
    hipLaunchKernelGGL(bucket_hist, dim3(NTILE), dim3(256), 0, stream, ei, bcnt);
    hipLaunchKernelGGL(bucket_scan, dim3(1), dim3(512), 0, stream, bcnt, bbase, bcur);
    hipLaunchKernelGGL(bucket_scatter, dim3(NTILE), dim3(256), 0, stream, ei, bcur, ebuf);
    hipLaunchKernelGGL(csr_build, dim3(NBUCKET), dim3(256), 0, stream,
                       ebuf, bbase, offsets, csr_row);
    hipLaunchKernelGGL(gather_softmax, dim3(GATHER_BLOCKS), dim3(256), 0, stream,
                       offsets, csr_row, WTb, MLPb, Sb, dtp);
    hipLaunchKernelGGL(cut_csr, dim3(CUT_BLOCKS), dim3(256), 0, stream,
                       offsets, csr_row, Sb, cutp);
    hipLaunchKernelGGL(ss_kernel, dim3(SS_BLOCKS), dim3(256), 0, stream, Sb, ssp);
    hipLaunchKernelGGL(reduce_ss, dim3(16), dim3(256), 0, stream, ssp, SS);
    hipLaunchKernelGGL(scalars_kernel, dim3(1), dim3(256), 0, stream, cutp, dtp, SS, out);
    hipLaunchKernelGGL(out_kernel, dim3(OUT_BLOCKS), dim3(256), 0, stream, x, Sb, Weff, beff, out);
}

// Round 6
// 335.631 us; speedup vs baseline: 2.8921x; 1.2063x over previous
//
#include <hip/hip_runtime.h>
#include <math.h>

#define N_NODES 100000
#define N_EDGES 1600000
#define IN_C    128
#define HID     256
#define KEIG    64
#define OUT_C   16

#define NPB      256                                   // nodes per bucket
#define NBUCKET  ((N_NODES + NPB - 1) / NPB)           // 391
#define EDGE_TILE 4096
#define NTILE    ((N_EDGES + EDGE_TILE - 1) / EDGE_TILE) // 391

#define TRANS_BLOCKS   ((N_NODES + 63) / 64)
#define GATHER_BLOCKS  2048
#define CUT_BLOCKS     2048
#define SSP_BLOCKS     512
#define OUT_BLOCKS     ((N_NODES + 255) / 256)

typedef __attribute__((ext_vector_type(8))) short short8;
typedef __attribute__((ext_vector_type(4))) float f32x4;

__device__ __forceinline__ float wave_sum(float v) {
#pragma unroll
    for (int m = 32; m; m >>= 1) v += __shfl_xor(v, m, 64);
    return v;
}
__device__ __forceinline__ float wave_max(float v) {
#pragma unroll
    for (int m = 32; m; m >>= 1) v = fmaxf(v, __shfl_xor(v, m, 64));
    return v;
}
__device__ __forceinline__ float bf2f(unsigned int u) {
    return __uint_as_float((u & 0xffffu) << 16);
}
__device__ __forceinline__ unsigned short f2bf(float f) {
    unsigned int u = __float_as_uint(f);
    u += 0x7fff + ((u >> 16) & 1);
    return (unsigned short)(u >> 16);
}

#define FMA4(P, s, W) \
    P.x = fmaf(s, W.x, P.x); P.y = fmaf(s, W.y, P.y); \
    P.z = fmaf(s, W.z, P.z); P.w = fmaf(s, W.w, P.w);

// ---------------- small precompute (+ zero bucket counts) ----------------
__global__ void prep_weff(const float* __restrict__ mlpxW, const float* __restrict__ mlpxb,
                          const float* __restrict__ finW, const float* __restrict__ finb,
                          float* __restrict__ Weff, float* __restrict__ beff,
                          int* __restrict__ bcnt) {
    int t = blockIdx.x * blockDim.x + threadIdx.x;
    const int NW = (IN_C + KEIG) * OUT_C;
    if (t < NW) {
        int k = t >> 4, o = t & 15;
        float acc;
        if (k < IN_C) {
            acc = 0.f;
            for (int c = 0; c < HID; ++c)
                acc += mlpxW[c * IN_C + k] * finW[o * (HID + KEIG) + c];
        } else {
            acc = finW[o * (HID + KEIG) + HID + (k - IN_C)];
        }
        Weff[k * OUT_C + o] = acc;
    }
    int tb = t - NW;
    if (tb >= 0 && tb < OUT_C) {
        float acc = finb[tb];
        for (int c = 0; c < HID; ++c) acc += mlpxb[c] * finW[tb * (HID + KEIG) + c];
        beff[tb] = acc;
    }
    int tz = t - (NW + OUT_C);
    if (tz >= 0 && tz <= NBUCKET) bcnt[tz] = 0;
}

// MLP_W [64, N] -> WTb [N, 64] bf16
__global__ void transpose_w(const float* __restrict__ W, unsigned short* __restrict__ WTb) {
    __shared__ float tile[64][65];
    int n0 = blockIdx.x * 64;
    int t = threadIdx.x;
    int tn = t & 63, tq = t >> 6;
#pragma unroll
    for (int kk = 0; kk < 16; ++kk) {
        int k = tq * 16 + kk;
        int n = n0 + tn;
        tile[k][tn] = (n < N_NODES) ? W[(long long)k * N_NODES + n] : 0.f;
    }
    __syncthreads();
    int tk = t & 63;
#pragma unroll
    for (int ii = 0; ii < 16; ++ii) {
        int n = n0 + tq * 16 + ii;
        if (n < N_NODES) WTb[(long long)n * 64 + tk] = f2bf(tile[tk][tq * 16 + ii]);
    }
}

// ---------------- bucket sort CSR build ----------------
__global__ void bucket_hist(const int* __restrict__ ei, int* __restrict__ bcnt) {
    __shared__ int h[NBUCKET];
    int t = threadIdx.x;
    for (int i = t; i < NBUCKET; i += 256) h[i] = 0;
    __syncthreads();
    int e0 = blockIdx.x * EDGE_TILE;
    int e1 = min(e0 + EDGE_TILE, N_EDGES);
    for (int e = e0 + t; e < e1; e += 256)
        atomicAdd(&h[ei[N_EDGES + e] >> 8], 1);
    __syncthreads();
    for (int i = t; i < NBUCKET; i += 256)
        if (h[i]) atomicAdd(&bcnt[i], h[i]);
}

__global__ void bucket_scan(const int* __restrict__ bcnt, int* __restrict__ bbase,
                            int* __restrict__ bcur) {
    __shared__ int sh[512];
    int t = threadIdx.x;
    int v = (t < NBUCKET) ? bcnt[t] : 0;
    sh[t] = v;
    __syncthreads();
    for (int d = 1; d < 512; d <<= 1) {
        int u = (t >= d) ? sh[t - d] : 0;
        __syncthreads();
        sh[t] += u;
        __syncthreads();
    }
    if (t < NBUCKET) { bbase[t] = sh[t] - v; bcur[t] = sh[t] - v; }
    if (t == 0) bbase[NBUCKET] = N_EDGES;
}

// partition edges into bucket regions; pack r | (local_col << 17)
__global__ void bucket_scatter(const int* __restrict__ ei, int* __restrict__ bcur,
                               int* __restrict__ ebuf) {
    __shared__ int h[NBUCKET];
    __shared__ int gb[NBUCKET];
    int t = threadIdx.x;
    for (int i = t; i < NBUCKET; i += 256) h[i] = 0;
    __syncthreads();
    int e0 = blockIdx.x * EDGE_TILE;
    int e1 = min(e0 + EDGE_TILE, N_EDGES);
    for (int e = e0 + t; e < e1; e += 256)
        atomicAdd(&h[ei[N_EDGES + e] >> 8], 1);
    __syncthreads();
    for (int i = t; i < NBUCKET; i += 256) {
        int c = h[i];
        gb[i] = c ? atomicAdd(&bcur[i], c) : 0;
        h[i] = 0;                                // reuse as local cursor
    }
    __syncthreads();
    for (int e = e0 + t; e < e1; e += 256) {
        int r = ei[e];
        int c = ei[N_EDGES + e];
        int b = c >> 8;
        int pos = gb[b] + atomicAdd(&h[b], 1);
        ebuf[pos] = r | ((c & 255) << 17);
    }
}

// one block per bucket: LDS hist + scan -> offsets; LDS cursors -> csr_row
__global__ void csr_build(const int* __restrict__ ebuf, const int* __restrict__ bbase,
                          int* __restrict__ offsets, int* __restrict__ csr_row) {
    __shared__ int hist[NPB];
    __shared__ int sh[NPB];
    __shared__ int curs[NPB];
    int b = blockIdx.x;
    int t = threadIdx.x;
    int s0 = bbase[b], s1 = bbase[b + 1];
    hist[t] = 0;
    __syncthreads();
    for (int i = s0 + t; i < s1; i += 256)
        atomicAdd(&hist[ebuf[i] >> 17], 1);
    __syncthreads();
    int v = hist[t];
    sh[t] = v;
    __syncthreads();
    for (int d = 1; d < 256; d <<= 1) {
        int u = (t >= d) ? sh[t - d] : 0;
        __syncthreads();
        sh[t] += u;
        __syncthreads();
    }
    int excl = s0 + sh[t] - v;
    int node = b * NPB + t;
    if (node < N_NODES) offsets[node] = excl;
    curs[t] = excl;
    __syncthreads();
    for (int i = s0 + t; i < s1; i += 256) {
        int pk = ebuf[i];
        int pos = atomicAdd(&curs[pk >> 17], 1);
        csr_row[pos] = pk & 0x1FFFF;
    }
    if (b == 0 && t == 0) offsets[N_NODES] = N_EDGES;
}

// ---------------- pass 1: gather + bias + softmax + deg_term ----------------
__global__ void gather_softmax(const int* __restrict__ offsets, const int* __restrict__ csr_row,
                               const unsigned short* __restrict__ WTb,
                               const float* __restrict__ MLPb,
                               unsigned short* __restrict__ Sb,
                               float* __restrict__ dtp) {
    int lane = threadIdx.x & 63;
    int wib = threadIdx.x >> 6;
    int gw = (blockIdx.x * blockDim.x + threadIdx.x) >> 6;
    int nw = (gridDim.x * blockDim.x) >> 6;
    float bias = MLPb[lane];
    float dacc = 0.f;
    for (int n = gw; n < N_NODES; n += nw) {
        int s0 = offsets[n], s1 = offsets[n + 1];
        float acc = bias;
        for (int base = s0; base < s1; base += 64) {
            int cnt = min(64, s1 - base);
            int rv = (lane < cnt) ? csr_row[base + lane] : 0;
            int j = 0;
            for (; j + 3 < cnt; j += 4) {
                int r0 = __shfl(rv, j, 64);
                int r1 = __shfl(rv, j + 1, 64);
                int r2 = __shfl(rv, j + 2, 64);
                int r3 = __shfl(rv, j + 3, 64);
                float v0 = bf2f(WTb[(long long)r0 * 64 + lane]);
                float v1 = bf2f(WTb[(long long)r1 * 64 + lane]);
                float v2 = bf2f(WTb[(long long)r2 * 64 + lane]);
                float v3 = bf2f(WTb[(long long)r3 * 64 + lane]);
                acc += (v0 + v1) + (v2 + v3);
            }
            for (; j < cnt; ++j) {
                int r = __shfl(rv, j, 64);
                acc += bf2f(WTb[(long long)r * 64 + lane]);
            }
        }
        float m = wave_max(acc);
        float e = __expf(acc - m);
        float sm = wave_sum(e);
        float sv = e / sm;
        Sb[(long long)n * 64 + lane] = f2bf(sv);
        dacc += (float)(s1 - s0) * sv * sv;
    }
    dacc = wave_sum(dacc);
    __shared__ float red[4];
    if (lane == 0) red[wib] = dacc;
    __syncthreads();
    if (threadIdx.x == 0) dtp[blockIdx.x] = red[0] + red[1] + red[2] + red[3];
}

// ---------------- pass 2: cut ----------------
__global__ void cut_csr(const int* __restrict__ offsets, const int* __restrict__ csr_row,
                        const unsigned short* __restrict__ Sb, float* __restrict__ cutp) {
    int lane = threadIdx.x & 63;
    int wib = threadIdx.x >> 6;
    int gw = (blockIdx.x * blockDim.x + threadIdx.x) >> 6;
    int nw = (gridDim.x * blockDim.x) >> 6;
    float acc = 0.f;
    for (int n = gw; n < N_NODES; n += nw) {
        float sc = bf2f(Sb[(long long)n * 64 + lane]);
        int s0 = offsets[n], s1 = offsets[n + 1];
        float g = 0.f;
        for (int base = s0; base < s1; base += 64) {
            int cnt = min(64, s1 - base);
            int rv = (lane < cnt) ? csr_row[base + lane] : 0;
            int j = 0;
            for (; j + 3 < cnt; j += 4) {
                int r0 = __shfl(rv, j, 64);
                int r1 = __shfl(rv, j + 1, 64);
                int r2 = __shfl(rv, j + 2, 64);
                int r3 = __shfl(rv, j + 3, 64);
                float v0 = bf2f(Sb[(long long)r0 * 64 + lane]);
                float v1 = bf2f(Sb[(long long)r1 * 64 + lane]);
                float v2 = bf2f(Sb[(long long)r2 * 64 + lane]);
                float v3 = bf2f(Sb[(long long)r3 * 64 + lane]);
                g += (v0 + v1) + (v2 + v3);
            }
            for (; j < cnt; ++j) {
                int r = __shfl(rv, j, 64);
                g += bf2f(Sb[(long long)r * 64 + lane]);
            }
        }
        acc += sc * g;
    }
    acc = wave_sum(acc);
    __shared__ float red[4];
    if (lane == 0) red[wib] = acc;
    __syncthreads();
    if (threadIdx.x == 0) cutp[blockIdx.x] = red[0] + red[1] + red[2] + red[3];
}

// ---------------- SS = S^T S via MFMA, per-block partials ----------------
// wave w owns SS rows [16w,16w+16); tiles (w, jt) jt=0..3.
// A/B frag layout (16x16x32 bf16): elem j = S[k=quad*8+j][16*strip + (lane&15)]
// C/D layout: col=lane&15, row=quad*4+reg
__global__ __launch_bounds__(256) void ss_mfma(const unsigned short* __restrict__ Sb,
                                               float* __restrict__ ssp) {
    __shared__ unsigned short Sr[32][66];   // +2 pad: frag reads conflict-free
    int t = threadIdx.x;
    int lane = t & 63;
    int w = t >> 6;
    int m = lane & 15;
    int quad = lane >> 4;
    int srow = t >> 3;        // 0..31
    int spart = t & 7;        // 0..7 (8 bf16 = 1 uint4)

    f32x4 a0 = {0.f,0.f,0.f,0.f}, a1 = {0.f,0.f,0.f,0.f};
    f32x4 a2 = {0.f,0.f,0.f,0.f}, a3 = {0.f,0.f,0.f,0.f};

    for (int base = blockIdx.x * 32; base < N_NODES; base += SSP_BLOCKS * 32) {
        const uint4* g = (const uint4*)(Sb + (long long)(base + srow) * 64 + spart * 8);
        uint4 d = *g;
        __syncthreads();                          // prev chunk fully read
        unsigned int* rowp = (unsigned int*)&Sr[srow][0];
        rowp[spart * 4 + 0] = d.x;
        rowp[spart * 4 + 1] = d.y;
        rowp[spart * 4 + 2] = d.z;
        rowp[spart * 4 + 3] = d.w;
        __syncthreads();                          // staging complete

        short8 f0, f1, f2, f3;
#pragma unroll
        for (int j = 0; j < 8; ++j) {
            int k = quad * 8 + j;
            f0[j] = (short)Sr[k][m];
            f1[j] = (short)Sr[k][16 + m];
            f2[j] = (short)Sr[k][32 + m];
            f3[j] = (short)Sr[k][48 + m];
        }
        short8 fa = (w == 0) ? f0 : (w == 1) ? f1 : (w == 2) ? f2 : f3;
        a0 = __builtin_amdgcn_mfma_f32_16x16x32_bf16(fa, f0, a0, 0, 0, 0);
        a1 = __builtin_amdgcn_mfma_f32_16x16x32_bf16(fa, f1, a1, 0, 0, 0);
        a2 = __builtin_amdgcn_mfma_f32_16x16x32_bf16(fa, f2, a2, 0, 0, 0);
        a3 = __builtin_amdgcn_mfma_f32_16x16x32_bf16(fa, f3, a3, 0, 0, 0);
    }

    float* dst = ssp + (size_t)blockIdx.x * 4096;
#pragma unroll
    for (int r = 0; r < 4; ++r) {
        int row = w * 16 + quad * 4 + r;
        dst[row * 64 +  0 + m] = a0[r];
        dst[row * 64 + 16 + m] = a1[r];
        dst[row * 64 + 32 + m] = a2[r];
        dst[row * 64 + 48 + m] = a3[r];
    }
}

__global__ void reduce_ss(const float* __restrict__ ssp, float* __restrict__ SS) {
    int e = blockIdx.x * blockDim.x + threadIdx.x;   // 0..4095
    float s = 0.f;
    for (int p = 0; p < SSP_BLOCKS; ++p) s += ssp[(size_t)p * 4096 + e];
    SS[e] = s;
}

// ---------------- scalar losses ----------------
__global__ void scalars_kernel(const float* __restrict__ cutp, const float* __restrict__ dtp,
                               const float* __restrict__ SS, float* __restrict__ out) {
    __shared__ float red[256];
    int t = threadIdx.x;
    float c = 0.f;
    for (int i = t; i < CUT_BLOCKS; i += 256) c += cutp[i];
    red[t] = c; __syncthreads();
    for (int s = 128; s; s >>= 1) { if (t < s) red[t] += red[t + s]; __syncthreads(); }
    float cut = red[0]; __syncthreads();

    float d = 0.f;
    for (int i = t; i < GATHER_BLOCKS; i += 256) d += dtp[i];
    red[t] = d; __syncthreads();
    for (int s = 128; s; s >>= 1) { if (t < s) red[t] += red[t + s]; __syncthreads(); }
    float dterm = red[0]; __syncthreads();

    float ss[16];
    float sq = 0.f;
#pragma unroll
    for (int j = 0; j < 16; ++j) { ss[j] = SS[t * 16 + j]; sq += ss[j] * ss[j]; }
    red[t] = sq; __syncthreads();
    for (int s = 128; s; s >>= 1) { if (t < s) red[t] += red[t + s]; __syncthreads(); }
    float nrm = sqrtf(red[0]); __syncthreads();

    float osq = 0.f;
#pragma unroll
    for (int j = 0; j < 16; ++j) {
        int idx = t * 16 + j;
        float v = ss[j] / nrm - ((idx % 65 == 0) ? 0.125f : 0.f);
        osq += v * v;
    }
    red[t] = osq; __syncthreads();
    for (int s = 128; s; s >>= 1) { if (t < s) red[t] += red[t + s]; __syncthreads(); }
    if (t == 0) {
        float loss = -(cut / dterm) + sqrtf(red[0]);
        out[(long long)N_NODES * OUT_C] = loss;
    }
}

// ---------------- output: barrier-free, one thread per row ----------------
__global__ __launch_bounds__(256) void out_kernel(const float* __restrict__ x,
                           const unsigned short* __restrict__ Sb,
                           const float* __restrict__ Weff, const float* __restrict__ beff,
                           float* __restrict__ out) {
    __shared__ float4 Wsh[192 * 4];   // Wsh[k*4+q] = Weff[k][4q..4q+3]
    __shared__ float bsh[16];
    int t = threadIdx.x;
    const float4* W4 = (const float4*)Weff;
    for (int i = t; i < 768; i += 256) Wsh[i] = W4[i];
    if (t < 16) bsh[t] = beff[t];
    __syncthreads();

    int r = blockIdx.x * 256 + t;
    if (r >= N_NODES) return;

    float4 p0 = make_float4(bsh[0], bsh[1], bsh[2], bsh[3]);
    float4 p1 = make_float4(bsh[4], bsh[5], bsh[6], bsh[7]);
    float4 p2 = make_float4(bsh[8], bsh[9], bsh[10], bsh[11]);
    float4 p3 = make_float4(bsh[12], bsh[13], bsh[14], bsh[15]);

    const float4* xr = (const float4*)(x + (long long)r * IN_C);
#pragma unroll 8
    for (int j = 0; j < 32; ++j) {
        float4 xv = xr[j];
        int k = j * 4;
        float xs[4] = {xv.x, xv.y, xv.z, xv.w};
#pragma unroll
        for (int c = 0; c < 4; ++c) {
            float s = xs[c];
            float4 w0 = Wsh[(k + c) * 4 + 0];
            float4 w1 = Wsh[(k + c) * 4 + 1];
            float4 w2 = Wsh[(k + c) * 4 + 2];
            float4 w3 = Wsh[(k + c) * 4 + 3];
            FMA4(p0, s, w0); FMA4(p1, s, w1); FMA4(p2, s, w2); FMA4(p3, s, w3);
        }
    }
    const uint2* sr = (const uint2*)(Sb + (long long)r * 64);
#pragma unroll 8
    for (int j = 0; j < 16; ++j) {
        uint2 u = sr[j];
        float xs[4] = {bf2f(u.x), bf2f(u.x >> 16), bf2f(u.y), bf2f(u.y >> 16)};
        int k = IN_C + j * 4;
#pragma unroll
        for (int c = 0; c < 4; ++c) {
            float s = xs[c];
            float4 w0 = Wsh[(k + c) * 4 + 0];
            float4 w1 = Wsh[(k + c) * 4 + 1];
            float4 w2 = Wsh[(k + c) * 4 + 2];
            float4 w3 = Wsh[(k + c) * 4 + 3];
            FMA4(p0, s, w0); FMA4(p1, s, w1); FMA4(p2, s, w2); FMA4(p3, s, w3);
        }
    }

    float m = fmaxf(fmaxf(fmaxf(p0.x, p0.y), fmaxf(p0.z, p0.w)),
                    fmaxf(fmaxf(fmaxf(p1.x, p1.y), fmaxf(p1.z, p1.w)),
                          fmaxf(fmaxf(fmaxf(p2.x, p2.y), fmaxf(p2.z, p2.w)),
                                fmaxf(fmaxf(p3.x, p3.y), fmaxf(p3.z, p3.w)))));
    float sum = __expf(p0.x - m) + __expf(p0.y - m) + __expf(p0.z - m) + __expf(p0.w - m)
              + __expf(p1.x - m) + __expf(p1.y - m) + __expf(p1.z - m) + __expf(p1.w - m)
              + __expf(p2.x - m) + __expf(p2.y - m) + __expf(p2.z - m) + __expf(p2.w - m)
              + __expf(p3.x - m) + __expf(p3.y - m) + __expf(p3.z - m) + __expf(p3.w - m);
    float lse = m + logf(sum);
    float4* o4 = (float4*)(out + (long long)r * OUT_C);
    o4[0] = make_float4(p0.x - lse, p0.y - lse, p0.z - lse, p0.w - lse);
    o4[1] = make_float4(p1.x - lse, p1.y - lse, p1.z - lse, p1.w - lse);
    o4[2] = make_float4(p2.x - lse, p2.y - lse, p2.z - lse, p2.w - lse);
    o4[3] = make_float4(p3.x - lse, p3.y - lse, p3.z - lse, p3.w - lse);
}

extern "C" void kernel_launch(void* const* d_in, const int* in_sizes, int n_in,
                              void* d_out, int out_size, void* d_ws, size_t ws_size,
                              hipStream_t stream) {
    const float* x     = (const float*)d_in[0];
    const int*   ei    = (const int*)d_in[1];
    const float* MLPW  = (const float*)d_in[2];
    const float* MLPb  = (const float*)d_in[3];
    const float* mlpxW = (const float*)d_in[4];
    const float* mlpxb = (const float*)d_in[5];
    const float* finW  = (const float*)d_in[6];
    const float* finb  = (const float*)d_in[7];
    float* out = (float*)d_out;
    float* ws  = (float*)d_ws;

    unsigned short* WTb = (unsigned short*)ws;                       // N*64 bf16
    unsigned short* Sb  = (unsigned short*)(ws + (size_t)N_NODES * 32); // N*64 bf16
    float* ssp  = ws + (size_t)N_NODES * 64;                         // 512*4096
    float* SS   = ssp + (size_t)SSP_BLOCKS * 4096;                   // 4096
    float* Weff = SS + 4096;                                         // 3072
    float* beff = Weff + 192 * 16;                                   // 16
    float* cutp = beff + 16;                                         // CUT_BLOCKS
    float* dtp  = cutp + CUT_BLOCKS;                                 // GATHER_BLOCKS
    int* ebuf    = (int*)(dtp + GATHER_BLOCKS);                      // E
    int* csr_row = ebuf + N_EDGES;                                   // E
    int* offsets = csr_row + N_EDGES;                                // N+1
    int* bcnt    = offsets + N_NODES + 1;                            // NBUCKET+1
    int* bbase   = bcnt + NBUCKET + 1;                               // NBUCKET+1
    int* bcur    = bbase + NBUCKET + 1;                              // NBUCKET

    hipLaunchKernelGGL(prep_weff, dim3(14), dim3(256), 0, stream,
                       mlpxW, mlpxb, finW, finb, Weff, beff, bcnt);
    hipLaunchKernelGGL(transpose_w, dim3(TRANS_BLOCKS), dim3(256), 0, stream, MLPW, WTb);
    hipLaunchKernelGGL(bucket_hist, dim3(NTILE), dim3(256), 0, stream, ei, bcnt);
    hipLaunchKernelGGL(bucket_scan, dim3(1), dim3(512), 0, stream, bcnt, bbase, bcur);
    hipLaunchKernelGGL(bucket_scatter, dim3(NTILE), dim3(256), 0, stream, ei, bcur, ebuf);
    hipLaunchKernelGGL(csr_build, dim3(NBUCKET), dim3(256), 0, stream,
                       ebuf, bbase, offsets, csr_row);
    hipLaunchKernelGGL(gather_softmax, dim3(GATHER_BLOCKS), dim3(256), 0, stream,
                       offsets, csr_row, WTb, MLPb, Sb, dtp);
    hipLaunchKernelGGL(cut_csr, dim3(CUT_BLOCKS), dim3(256), 0, stream,
                       offsets, csr_row, Sb, cutp);
    hipLaunchKernelGGL(ss_mfma, dim3(SSP_BLOCKS), dim3(256), 0, stream, Sb, ssp);
    hipLaunchKernelGGL(reduce_ss, dim3(16), dim3(256), 0, stream, ssp, SS);
    hipLaunchKernelGGL(scalars_kernel, dim3(1), dim3(256), 0, stream, cutp, dtp, SS, out);
    hipLaunchKernelGGL(out_kernel, dim3(OUT_BLOCKS), dim3(256), 0, stream, x, Sb, Weff, beff, out);
}